// Round 12
// baseline (1134.336 us; speedup 1.0000x reference)
//
#include <hip/hip_runtime.h>

typedef unsigned short u16;
typedef unsigned int u32;
typedef __bf16 bf16x8 __attribute__((ext_vector_type(8)));
typedef _Float16 f16;
typedef f16 f16x8 __attribute__((ext_vector_type(8)));
typedef float f32x4 __attribute__((ext_vector_type(4)));
typedef u32 u32x2 __attribute__((ext_vector_type(2)));

#define DEVFN __device__ __forceinline__

constexpr int kB = 2, kS = 1024, kD = 2048, kH = 16, kKVH = 4, kHD = 128;
constexpr int kHID = 4096, kE = 8;
constexpr int kRows = kB * kS;               // 2048 tokens
constexpr int kQKVN = kH*kHD + 2*kKVH*kHD;   // 3072 fused qkv cols
constexpr int kSlotsPad = 5120;              // 40 tiles x 128
constexpr int kMaxTiles = 40;
constexpr float kEps = 1e-5f;
constexpr float kNeg = -1000000000.0f;
constexpr float kScale = 0.08838834764831845f;

DEVFN u16 f2bf(float f) {
  u32 u = __float_as_uint(f);
  return (u16)((u + 0x7fffu + ((u >> 16) & 1u)) >> 16);
}
DEVFN float bf2f(u16 u) { u32 v = ((u32)u) << 16; return __uint_as_float(v); }

DEVFN void split8v(float4 a, float4 b, f16x8& hi, f16x8& lo) {
  float v[8] = {a.x, a.y, a.z, a.w, b.x, b.y, b.z, b.w};
  #pragma unroll
  for (int e = 0; e < 8; ++e) {
    f16 h = (f16)v[e];
    hi[e] = h;
    lo[e] = (f16)(v[e] - (float)h);
  }
}

DEVFN void gll16(const void* g, void* l) {
  __builtin_amdgcn_global_load_lds(
      (const __attribute__((address_space(1))) void*)g,
      (__attribute__((address_space(3))) void*)l, 16, 0, 0);
}

// 4 f32 -> 4 bf16 (RNE, value-identical to f2bf) packed in 64 bits
DEVFN u32x2 pk4bf(float a, float b, float c, float d) {
  union { __bf16 h[4]; u32x2 w; } u;
  u.h[0] = (__bf16)a; u.h[1] = (__bf16)b;
  u.h[2] = (__bf16)c; u.h[3] = (__bf16)d;
  return u.w;
}

// ---- T4 sync helpers. vmcnt wait folded INTO the pre-compute barrier so every
// wave retires its own gll16 A-stage BEFORE arriving; barrier-exit then
// guarantees all waves' A-tiles landed (fixes round-11 cross-wave race).
DEVFN void baronly() { __builtin_amdgcn_sched_barrier(0);
  __builtin_amdgcn_s_barrier();
  __builtin_amdgcn_sched_barrier(0); }
DEVFN void barlgkm() { __builtin_amdgcn_sched_barrier(0);
  asm volatile("s_waitcnt lgkmcnt(0)" ::: "memory");
  __builtin_amdgcn_s_barrier();
  __builtin_amdgcn_sched_barrier(0); }
DEVFN void barvm20() { __builtin_amdgcn_sched_barrier(0);
  asm volatile("s_waitcnt vmcnt(20) lgkmcnt(0)" ::: "memory");
  __builtin_amdgcn_s_barrier();
  __builtin_amdgcn_sched_barrier(0); }
DEVFN void barvm0() { __builtin_amdgcn_sched_barrier(0);
  asm volatile("s_waitcnt vmcnt(0) lgkmcnt(0)" ::: "memory");
  __builtin_amdgcn_s_barrier();
  __builtin_amdgcn_sched_barrier(0); }

// ---------------- RMSNorm + f16 split ----------------
__global__ __launch_bounds__(256) void rms_split_kernel(const float* __restrict__ in,
    const float* __restrict__ w, f16* __restrict__ oh, f16* __restrict__ ol) {
  int row = blockIdx.x, tid = threadIdx.x;
  const float* x = in + (size_t)row * kD;
  float4 v0 = *(const float4*)&x[tid*8];
  float4 v1 = *(const float4*)&x[tid*8+4];
  float ss = v0.x*v0.x+v0.y*v0.y+v0.z*v0.z+v0.w*v0.w
           + v1.x*v1.x+v1.y*v1.y+v1.z*v1.z+v1.w*v1.w;
  #pragma unroll
  for (int off = 32; off; off >>= 1) ss += __shfl_xor(ss, off);
  __shared__ float red[4];
  if ((tid & 63) == 0) red[tid >> 6] = ss;
  __syncthreads();
  float tot = red[0] + red[1] + red[2] + red[3];
  float rs = rsqrtf(tot * (1.0f/kD) + kEps);
  float4 w0 = *(const float4*)&w[tid*8];
  float4 w1 = *(const float4*)&w[tid*8+4];
  float4 o0, o1;
  o0.x = v0.x*rs*w0.x; o0.y = v0.y*rs*w0.y; o0.z = v0.z*rs*w0.z; o0.w = v0.w*rs*w0.w;
  o1.x = v1.x*rs*w1.x; o1.y = v1.y*rs*w1.y; o1.z = v1.z*rs*w1.z; o1.w = v1.w*rs*w1.w;
  f16x8 hi, lo;
  split8v(o0, o1, hi, lo);
  *(f16x8*)&oh[(size_t)row*kD + tid*8] = hi;
  *(f16x8*)&ol[(size_t)row*kD + tid*8] = lo;
}

__global__ __launch_bounds__(256) void rms_bf16_kernel(const float* __restrict__ in,
    const float* __restrict__ w, u16* __restrict__ out) {
  int row = blockIdx.x, tid = threadIdx.x;
  const float* x = in + (size_t)row * kD;
  float4 v0 = *(const float4*)&x[tid*8];
  float4 v1 = *(const float4*)&x[tid*8+4];
  float ss = v0.x*v0.x+v0.y*v0.y+v0.z*v0.z+v0.w*v0.w
           + v1.x*v1.x+v1.y*v1.y+v1.z*v1.z+v1.w*v1.w;
  #pragma unroll
  for (int off = 32; off; off >>= 1) ss += __shfl_xor(ss, off);
  __shared__ float red[4];
  if ((tid & 63) == 0) red[tid >> 6] = ss;
  __syncthreads();
  float tot = red[0] + red[1] + red[2] + red[3];
  float rs = rsqrtf(tot * (1.0f/kD) + kEps);
  float4 w0 = *(const float4*)&w[tid*8];
  float4 w1 = *(const float4*)&w[tid*8+4];
  union { int4 i4; u16 u[8]; } pk;
  pk.u[0] = f2bf(v0.x*rs*w0.x); pk.u[1] = f2bf(v0.y*rs*w0.y);
  pk.u[2] = f2bf(v0.z*rs*w0.z); pk.u[3] = f2bf(v0.w*rs*w0.w);
  pk.u[4] = f2bf(v1.x*rs*w1.x); pk.u[5] = f2bf(v1.y*rs*w1.y);
  pk.u[6] = f2bf(v1.z*rs*w1.z); pk.u[7] = f2bf(v1.w*rs*w1.w);
  *(int4*)&out[(size_t)row*kD + tid*8] = pk.i4;
}

// ------- transpose + f16-split (qkv/wo weights): f32 [R][C] -> hi/lo [C+noff][R] -------
__global__ void transpose_split_kernel(const float* __restrict__ in,
    f16* __restrict__ hi, f16* __restrict__ lo, int R, int C, int noff, int ldout) {
  __shared__ float tile[32][33];
  int c0 = blockIdx.x * 32, r0 = blockIdx.y * 32;
  int tx = threadIdx.x, ty = threadIdx.y;
  #pragma unroll
  for (int i = 0; i < 32; i += 8)
    tile[ty + i][tx] = in[(size_t)(r0 + ty + i) * C + c0 + tx];
  __syncthreads();
  #pragma unroll
  for (int i = 0; i < 32; i += 8) {
    float v = tile[tx][ty + i];
    f16 h = (f16)v;
    size_t o = (size_t)(noff + c0 + ty + i) * ldout + r0 + tx;
    hi[o] = h;
    lo[o] = (f16)(v - (float)h);
  }
}

// ------- V transpose + split: qkv V cols -> vTh/vTl [b][kvh*128+d][S] f16 -------
__global__ void vt_split_kernel(const float* __restrict__ qkv,
    f16* __restrict__ vTh, f16* __restrict__ vTl) {
  __shared__ float tile[32][33];
  int s0 = blockIdx.x * 32, c0 = blockIdx.y * 32, b = blockIdx.z;
  int tx = threadIdx.x, ty = threadIdx.y;
  #pragma unroll
  for (int i = 0; i < 32; i += 8)
    tile[ty + i][tx] = qkv[(size_t)(b*kS + s0 + ty + i) * kQKVN + kH*kHD + kKVH*kHD + c0 + tx];
  __syncthreads();
  #pragma unroll
  for (int i = 0; i < 32; i += 8) {
    float v = tile[tx][ty + i];
    f16 h = (f16)v;
    size_t o = (size_t)(b*kKVH*kHD + c0 + ty + i) * kS + s0 + tx;
    vTh[o] = h;
    vTl[o] = (f16)(v - (float)h);
  }
}

// ---------------- split-f16 GEMM via global_load_lds ----------------
template<bool ADDX>
__global__ __launch_bounds__(256) void gemm_sf16_kernel(
    const f16* __restrict__ Ah0, const f16* __restrict__ Al0, int lda,
    const f16* __restrict__ Bh0, const f16* __restrict__ Bl0,
    float* __restrict__ C, int ldc, int coff,
    const float* __restrict__ X, int ldx, int K) {
  __shared__ __align__(16) u16 Ah[128*64], Al[128*64], Bh[128*64], Bl[128*64];
  int tid = threadIdx.x, lane = tid & 63, w = tid >> 6;
  int bm = blockIdx.y * 128, bn = blockIdx.x * 128;
  int wr = w >> 1, wc = w & 1;
  int hg = lane >> 4, lid = lane & 15;
  f32x4 acc[4][4] = {};
  const f16 *aH[4], *aL[4], *bH[4], *bL[4];
  #pragma unroll
  for (int j = 0; j < 4; ++j) {
    int r = w*32 + j*8 + (lane >> 3);
    int colc = ((lane & 7) ^ (r & 7)) * 8;
    aH[j] = Ah0 + (size_t)(bm + r) * lda + colc;
    aL[j] = Al0 + (size_t)(bm + r) * lda + colc;
    bH[j] = Bh0 + (size_t)(bn + r) * K + colc;
    bL[j] = Bl0 + (size_t)(bn + r) * K + colc;
  }
  const char* AhB = (const char*)Ah; const char* AlB = (const char*)Al;
  const char* BhB = (const char*)Bh; const char* BlB = (const char*)Bl;
  for (int kt = 0; kt < K; kt += 64) {
    __syncthreads();
    #pragma unroll
    for (int j = 0; j < 4; ++j) {
      int lb = w*2048 + j*512;
      gll16(aH[j] + kt, &Ah[lb]);
      gll16(aL[j] + kt, &Al[lb]);
      gll16(bH[j] + kt, &Bh[lb]);
      gll16(bL[j] + kt, &Bl[lb]);
    }
    __syncthreads();
    #pragma unroll
    for (int kk = 0; kk < 2; ++kk) {
      f16x8 ah[4], al[4], bh[4], bl[4];
      #pragma unroll
      for (int f = 0; f < 4; ++f) {
        int rA = wr*64 + f*16 + lid;
        int oA = (rA*128 + kk*64 + hg*16) ^ ((rA & 7) << 4);
        ah[f] = *(const f16x8*)(AhB + oA);
        al[f] = *(const f16x8*)(AlB + oA);
        int rB = wc*64 + f*16 + lid;
        int oB = (rB*128 + kk*64 + hg*16) ^ ((rB & 7) << 4);
        bh[f] = *(const f16x8*)(BhB + oB);
        bl[f] = *(const f16x8*)(BlB + oB);
      }
      __builtin_amdgcn_s_setprio(1);
      #pragma unroll
      for (int i = 0; i < 4; ++i)
        #pragma unroll
        for (int j = 0; j < 4; ++j) {
          acc[i][j] = __builtin_amdgcn_mfma_f32_16x16x32_f16(ah[i], bh[j], acc[i][j], 0, 0, 0);
          acc[i][j] = __builtin_amdgcn_mfma_f32_16x16x32_f16(ah[i], bl[j], acc[i][j], 0, 0, 0);
          acc[i][j] = __builtin_amdgcn_mfma_f32_16x16x32_f16(al[i], bh[j], acc[i][j], 0, 0, 0);
        }
      __builtin_amdgcn_s_setprio(0);
    }
  }
  #pragma unroll
  for (int i = 0; i < 4; ++i) {
    #pragma unroll
    for (int rr = 0; rr < 4; ++rr) {
      size_t gr = (size_t)(bm + wr*64 + i*16 + hg*4 + rr);
      #pragma unroll
      for (int j = 0; j < 4; ++j) {
        int gc = bn + wc*64 + j*16 + lid;
        float v = acc[i][j][rr];
        if (ADDX) v += X[gr * ldx + gc];
        C[gr * ldc + coff + gc] = v;
      }
    }
  }
}

// ---------------- RoPE: Q in-place, K -> pre-split f16 buffers ----------------
__global__ __launch_bounds__(256) void rope_kernel(float* __restrict__ qkv,
    const float* __restrict__ fc, const float* __restrict__ fs,
    f16* __restrict__ Kh, f16* __restrict__ Kl) {
  int idx = blockIdx.x * 256 + threadIdx.x;
  constexpr int NQ = kB*kS*kH*(kHD/2);
  constexpr int NK = kB*kS*kKVH*(kHD/2);
  if (idx < NQ) {
    int i = idx & 63, h = (idx >> 6) & 15, s = (idx >> 10) & 1023, b = idx >> 20;
    size_t base = ((size_t)(b*kS + s))*kQKVN + h*kHD + 2*i;
    float c = fc[s*64 + i], sn = fs[s*64 + i];
    float xr = qkv[base], xi = qkv[base+1];
    qkv[base]   = xr*c - xi*sn;
    qkv[base+1] = xr*sn + xi*c;
  } else {
    int j = idx - NQ; if (j >= NK) return;
    int i = j & 63, h = (j >> 6) & 3, s = (j >> 8) & 1023, b = j >> 18;
    size_t src = ((size_t)(b*kS + s))*kQKVN + kH*kHD + h*kHD + 2*i;
    float c = fc[s*64 + i], sn = fs[s*64 + i];
    float xr = qkv[src], xi = qkv[src+1];
    float o0 = xr*c - xi*sn, o1 = xr*sn + xi*c;
    size_t dst = (((size_t)(b*kKVH + h))*kS + s)*kHD + 2*i;
    f16 h0 = (f16)o0, h1 = (f16)o1;
    Kh[dst]   = h0; Kl[dst]   = (f16)(o0 - (float)h0);
    Kh[dst+1] = h1; Kl[dst+1] = (f16)(o1 - (float)h1);
  }
}

// ---------------- split-f16 MFMA flash attention (pre-split K/V) ----------------
__global__ __launch_bounds__(256) void attn_sf16_kernel(const float* __restrict__ qkv,
    const f16* __restrict__ Ksh, const f16* __restrict__ Ksl,
    const f16* __restrict__ vTh, const f16* __restrict__ vTl,
    f16* __restrict__ outh, f16* __restrict__ outl) {
  int qt = (int)gridDim.x - 1 - blockIdx.x;
  int h = blockIdx.y, b = blockIdx.z;
  int kvh = h >> 2;
  int q0 = qt * 64;
  __shared__ __align__(16) char Kh[64*128*2], Kl[64*128*2];
  __shared__ __align__(16) char Vh[128*64*2], Vl[128*64*2];
  __shared__ __align__(16) char Ph[4][16*64*2], Pl[4][16*64*2];
  int tid = threadIdx.x, lane = tid & 63, w = tid >> 6;
  int hg = lane >> 4, lid = lane & 15;

  f16x8 qh[4], ql[4];
  {
    const float* qrow = qkv + (size_t)(b*kS + q0 + w*16 + lid) * kQKVN + h*kHD;
    #pragma unroll
    for (int ks = 0; ks < 4; ++ks) {
      float4 a = *(const float4*)(qrow + ks*32 + hg*8);
      float4 c = *(const float4*)(qrow + ks*32 + hg*8 + 4);
      split8v(a, c, qh[ks], ql[ks]);
    }
  }
  f32x4 oacc[8] = {};
  float m[4] = {-3.0e38f, -3.0e38f, -3.0e38f, -3.0e38f};
  float lsum[4] = {};
  char* Phw = Ph[w];
  char* Plw = Pl[w];

  for (int kt = 0; kt <= qt; ++kt) {
    __syncthreads();
    {
      int r = tid >> 2, c0 = (tid & 3) * 32;
      const f16* khr = Ksh + ((size_t)(b*kKVH + kvh)*kS + kt*64 + r) * kHD + c0;
      const f16* klr = Ksl + ((size_t)(b*kKVH + kvh)*kS + kt*64 + r) * kHD + c0;
      #pragma unroll
      for (int s8 = 0; s8 < 4; ++s8) {
        int4 hi = *(const int4*)(khr + s8*8);
        int4 lo = *(const int4*)(klr + s8*8);
        int off = (r*256 + c0*2 + s8*16) ^ ((r & 7) << 4);
        *(int4*)(Kh + off) = hi;
        *(int4*)(Kl + off) = lo;
      }
    }
    {
      int r = tid >> 1, c0 = (tid & 1) * 32;
      const f16* vhr = vTh + (size_t)(b*kKVH*kHD + kvh*kHD + r) * kS + kt*64 + c0;
      const f16* vlr = vTl + (size_t)(b*kKVH*kHD + kvh*kHD + r) * kS + kt*64 + c0;
      #pragma unroll
      for (int s8 = 0; s8 < 4; ++s8) {
        int4 hi = *(const int4*)(vhr + s8*8);
        int4 lo = *(const int4*)(vlr + s8*8);
        int off = (r*128 + c0*2 + s8*16) ^ ((r & 7) << 4);
        *(int4*)(Vh + off) = hi;
        *(int4*)(Vl + off) = lo;
      }
    }
    __syncthreads();

    f32x4 sacc[4] = {};
    __builtin_amdgcn_s_setprio(1);
    #pragma unroll
    for (int ks = 0; ks < 4; ++ks) {
      #pragma unroll
      for (int j = 0; j < 4; ++j) {
        int rB = j*16 + lid;
        int off = (rB*256 + ks*64 + hg*16) ^ ((rB & 7) << 4);
        f16x8 kh = *(const f16x8*)(Kh + off);
        f16x8 klo = *(const f16x8*)(Kl + off);
        sacc[j] = __builtin_amdgcn_mfma_f32_16x16x32_f16(qh[ks], kh, sacc[j], 0, 0, 0);
        sacc[j] = __builtin_amdgcn_mfma_f32_16x16x32_f16(qh[ks], klo, sacc[j], 0, 0, 0);
        sacc[j] = __builtin_amdgcn_mfma_f32_16x16x32_f16(ql[ks], kh, sacc[j], 0, 0, 0);
      }
    }
    __builtin_amdgcn_s_setprio(0);
    float s[4][4], ps[4][4];
    bool diag = (kt == qt);
    #pragma unroll
    for (int j = 0; j < 4; ++j)
      #pragma unroll
      for (int r = 0; r < 4; ++r) {
        float v = sacc[j][r] * kScale;
        if (diag) {
          int kvabs = kt*64 + j*16 + lid;
          int qabs = q0 + w*16 + hg*4 + r;
          if (kvabs > qabs) v = kNeg;
        }
        s[j][r] = v;
      }
    float pm[4], cf[4];
    #pragma unroll
    for (int r = 0; r < 4; ++r) {
      pm[r] = fmaxf(fmaxf(s[0][r], s[1][r]), fmaxf(s[2][r], s[3][r]));
      #pragma unroll
      for (int msk = 1; msk < 16; msk <<= 1) pm[r] = fmaxf(pm[r], __shfl_xor(pm[r], msk));
      float mn = fmaxf(m[r], pm[r]);
      cf[r] = __expf(m[r] - mn);
      m[r] = mn;
    }
    #pragma unroll
    for (int j2 = 0; j2 < 8; ++j2)
      #pragma unroll
      for (int r = 0; r < 4; ++r) oacc[j2][r] *= cf[r];
    float rs[4] = {};
    #pragma unroll
    for (int j = 0; j < 4; ++j)
      #pragma unroll
      for (int r = 0; r < 4; ++r) {
        float p = __expf(s[j][r] - m[r]);
        ps[j][r] = p;
        rs[r] += p;
      }
    #pragma unroll
    for (int r = 0; r < 4; ++r) lsum[r] = lsum[r]*cf[r] + rs[r];
    #pragma unroll
    for (int j = 0; j < 4; ++j)
      #pragma unroll
      for (int r = 0; r < 4; ++r) {
        int q = hg*4 + r;
        int off = (q*128 + (j*16 + lid)*2) ^ ((q & 7) << 4);
        f16 ph = (f16)ps[j][r];
        *(f16*)(Phw + off) = ph;
        *(f16*)(Plw + off) = (f16)(ps[j][r] - (float)ph);
      }
    #pragma unroll
    for (int kk2 = 0; kk2 < 2; ++kk2) {
      int oP = (lid*128 + kk2*64 + hg*16) ^ ((lid & 7) << 4);
      f16x8 pa_h = *(const f16x8*)(Phw + oP);
      f16x8 pa_l = *(const f16x8*)(Plw + oP);
      __builtin_amdgcn_s_setprio(1);
      #pragma unroll
      for (int j2 = 0; j2 < 8; ++j2) {
        int rV = j2*16 + lid;
        int off = (rV*128 + kk2*64 + hg*16) ^ ((rV & 7) << 4);
        f16x8 vh = *(const f16x8*)(Vh + off);
        f16x8 vl = *(const f16x8*)(Vl + off);
        oacc[j2] = __builtin_amdgcn_mfma_f32_16x16x32_f16(pa_h, vh, oacc[j2], 0, 0, 0);
        oacc[j2] = __builtin_amdgcn_mfma_f32_16x16x32_f16(pa_h, vl, oacc[j2], 0, 0, 0);
        oacc[j2] = __builtin_amdgcn_mfma_f32_16x16x32_f16(pa_l, vh, oacc[j2], 0, 0, 0);
      }
      __builtin_amdgcn_s_setprio(0);
    }
  }
  #pragma unroll
  for (int r = 0; r < 4; ++r) {
    #pragma unroll
    for (int msk = 1; msk < 16; msk <<= 1) lsum[r] += __shfl_xor(lsum[r], msk);
    lsum[r] = 1.f / lsum[r];
  }
  #pragma unroll
  for (int j2 = 0; j2 < 8; ++j2)
    #pragma unroll
    for (int r = 0; r < 4; ++r) {
      size_t o = (size_t)(b*kS + q0 + w*16 + hg*4 + r) * kD + h*kHD + j2*16 + lid;
      float v = oacc[j2][r] * lsum[r];
      f16 hh = (f16)v;
      outh[o] = hh;
      outl[o] = (f16)(v - (float)hh);
    }
}

// ---------------- gate / prefix+table ----------------
__global__ void zero_counts_kernel(int* counts) {
  if (threadIdx.x < kE) counts[threadIdx.x] = 0;
}

__global__ __launch_bounds__(64) void gate_kernel(const float* __restrict__ h1,
    const float* __restrict__ wn, const float* __restrict__ gw,
    int* __restrict__ packA, int* __restrict__ packB,
    float* __restrict__ cA, float* __restrict__ cB,
    int* __restrict__ lists, int* __restrict__ counts) {
  int row = blockIdx.x, lane = threadIdx.x;
  const float* x = h1 + (size_t)row * kD;
  float ss = 0.f;
  for (int d = lane; d < kD; d += 64) { float v = x[d]; ss = fmaf(v, v, ss); }
  #pragma unroll
  for (int off = 32; off; off >>= 1) ss += __shfl_xor(ss, off);
  float rs = rsqrtf(ss * (1.0f/kD) + kEps);
  float acc[kE] = {};
  for (int d = lane; d < kD; d += 64) {
    float g = x[d] * rs * wn[d];
    const float* gr = gw + (size_t)d * kE;
    #pragma unroll
    for (int e = 0; e < kE; ++e) acc[e] = fmaf(g, gr[e], acc[e]);
  }
  #pragma unroll
  for (int e = 0; e < kE; ++e)
    #pragma unroll
    for (int off = 32; off; off >>= 1) acc[e] += __shfl_xor(acc[e], off);
  if (lane == 0) {
    int i1 = 0; float l1 = acc[0];
    #pragma unroll
    for (int e = 1; e < kE; ++e) if (acc[e] > l1) { l1 = acc[e]; i1 = e; }
    int i2 = -1; float l2 = -3.4e38f;
    #pragma unroll
    for (int e = 0; e < kE; ++e) if (e != i1 && acc[e] > l2) { l2 = acc[e]; i2 = e; }
    float e2 = __expf(l2 - l1);
    float inv = 1.f / (1.f + e2);
    int p1 = atomicAdd(&counts[i1], 1); lists[i1*kRows + p1] = row;
    int p2 = atomicAdd(&counts[i2], 1); lists[i2*kRows + p2] = row;
    packA[row] = i1*2048 + p1; cA[row] = inv;
    packB[row] = i2*2048 + p2; cB[row] = e2 * inv;
  }
}

__global__ void prefix_kernel(const int* __restrict__ counts,
    int* __restrict__ padbase, int* __restrict__ tileTab) {
  if (threadIdx.x == 0) {
    int base = 0, idx = 0;
    for (int e = 0; e < kE; ++e) {
      padbase[e] = base;
      int nt = (counts[e] + 127) >> 7;
      for (int t = 0; t < nt; ++t) tileTab[idx++] = (e << 8) | t;
      base += nt << 7;
    }
    for (; idx < kMaxTiles; ++idx) tileTab[idx] = -1;
  }
}

// ------- MoE up-proj: BK=64, depth-2 B prefetch, vmcnt-in-barrier (T4, r11 race fixed) -------
// grid (g, tile): g fastest -> same-B-slice blocks 64 apart -> same XCD.
__global__ __launch_bounds__(256) void gemm_up_kernel(
    const u16* __restrict__ A, const float* __restrict__ W1, const float* __restrict__ W3,
    u16* __restrict__ hid, const int* __restrict__ lists,
    const int* __restrict__ counts, const int* __restrict__ padbase,
    const int* __restrict__ tileTab) {
  int tab = tileTab[blockIdx.y];
  if (tab < 0) return;
  int e = tab >> 8, mb = tab & 255;
  int cnt = counts[e];
  int bm = mb * 128;
  int slot0 = padbase[e] + bm;
  const int* ids = lists + e * kRows;
  int g = blockIdx.x;
  __shared__ __align__(16) char SM[65536];
  u16* As[2]   = { (u16*)SM, (u16*)(SM + 16384) };
  char* B1s[2] = { SM + 32768, SM + 40960 };
  char* B3s[2] = { SM + 49152, SM + 57344 };
  int tid = threadIdx.x, lane = tid & 63, w = tid >> 6;
  int wr = w >> 1, wc = w & 1;
  int hg = lane >> 4, lid = lane & 15;
  f32x4 acc[4][4] = {};

  const u16* aP[4];
  #pragma unroll
  for (int j = 0; j < 4; ++j) {
    int r = w*32 + j*8 + (lane >> 3);
    int colc = ((lane & 7) ^ (r & 7)) * 8;
    int rr = bm + r; if (rr >= cnt) rr = cnt - 1;
    aP[j] = A + (size_t)ids[rr] * kD + colc;
  }
  int c0 = (tid & 31) * 2, hk = tid >> 5;
  const float* b1e = W1 + (size_t)e*kD*kHID + (size_t)g*64 + c0;
  const float* b3e = W3 + (size_t)e*kD*kHID + (size_t)g*64 + c0;
  int wOffX[2], wOffY[2];
  #pragma unroll
  for (int q = 0; q < 2; ++q) {
    int k0b = (hk*8 + q*4) * 2;
    wOffX[q] = (c0*128 + k0b) ^ ((c0 & 7) << 4);
    wOffY[q] = ((c0+1)*128 + k0b) ^ (((c0+1) & 7) << 4);
  }
  float2 r1E[8], r3E[8], r1O[8], r3O[8];

  auto stageA = [&](int buf, int t) {   // 4 VMEM
    int kt = t * 64;
    #pragma unroll
    for (int j = 0; j < 4; ++j) gll16(aP[j] + kt, &As[buf][w*2048 + j*512]);
  };
  auto loadB = [&](float2* r1, float2* r3, int t) {   // 16 VMEM
    int kt = t * 64;
    #pragma unroll
    for (int j = 0; j < 8; ++j) {
      size_t ko = (size_t)(kt + hk*8 + j) * kHID;
      r1[j] = *(const float2*)(b1e + ko);
      r3[j] = *(const float2*)(b3e + ko);
    }
  };
  auto writeB = [&](int buf, float2* r1, float2* r3) {  // compiler auto-waits on regs
    #pragma unroll
    for (int q = 0; q < 2; ++q) {
      *(u32x2*)(B1s[buf] + wOffX[q]) = pk4bf(r1[q*4].x, r1[q*4+1].x, r1[q*4+2].x, r1[q*4+3].x);
      *(u32x2*)(B1s[buf] + wOffY[q]) = pk4bf(r1[q*4].y, r1[q*4+1].y, r1[q*4+2].y, r1[q*4+3].y);
      *(u32x2*)(B3s[buf] + wOffX[q]) = pk4bf(r3[q*4].x, r3[q*4+1].x, r3[q*4+2].x, r3[q*4+3].x);
      *(u32x2*)(B3s[buf] + wOffY[q]) = pk4bf(r3[q*4].y, r3[q*4+1].y, r3[q*4+2].y, r3[q*4+3].y);
    }
  };
  auto compute = [&](int buf) {
    const char* AsB = (const char*)As[buf];
    const char* Bb = wc ? B3s[buf] : B1s[buf];
    #pragma unroll
    for (int kk = 0; kk < 2; ++kk) {
      bf16x8 af[4], bfv[4];
      #pragma unroll
      for (int f = 0; f < 4; ++f) {
        int rA = wr*64 + f*16 + lid;
        af[f] = *(const bf16x8*)(AsB + ((rA*128 + kk*64 + hg*16) ^ ((rA & 7) << 4)));
        int rB = f*16 + lid;
        bfv[f] = *(const bf16x8*)(Bb + ((rB*128 + kk*64 + hg*16) ^ ((rB & 7) << 4)));
      }
      __builtin_amdgcn_s_setprio(1);
      #pragma unroll
      for (int i = 0; i < 4; ++i)
        #pragma unroll
        for (int j = 0; j < 4; ++j)
          acc[i][j] = __builtin_amdgcn_mfma_f32_16x16x32_bf16(af[i], bfv[j], acc[i][j], 0, 0, 0);
      __builtin_amdgcn_s_setprio(0);
    }
  };

  constexpr int NT = kD / 64;  // 32 (even)
  // prologue: all waves retire their stageAs via writeB's auto-wait (E is newer)
  stageA(0, 0); stageA(1, 1);
  loadB(r1E, r3E, 0);
  loadB(r1O, r3O, 1);
  writeB(0, r1E, r3E);
  barlgkm();
  for (int t = 0; t + 2 < NT; t += 2) {
    loadB(r1E, r3E, t+2);
    compute(0);                 // tile t
    baronly();
    stageA(0, t+2);
    writeB(1, r1O, r3O);        // tile t+1
    barvm20();                  // retires stageA(1,t+1) in ALL waves, publishes B
    loadB(r1O, r3O, t+3);
    compute(1);                 // tile t+1
    baronly();
    stageA(1, t+3);
    writeB(0, r1E, r3E);        // tile t+2
    barvm20();                  // retires stageA(0,t+2), publishes B
  }
  // tail: tiles NT-2 (buf0, ready), NT-1 (buf1)
  compute(0);
  baronly();
  writeB(1, r1O, r3O);
  barvm0();
  compute(1);
  __syncthreads();

  // epilogue: exchange g1 (wc=0) -> silu(g1)*g3 (wc=1), write hid
  float* Xch = (float*)SM;
  if (wc == 0) {
    #pragma unroll
    for (int i = 0; i < 4; ++i)
      #pragma unroll
      for (int rr = 0; rr < 4; ++rr) {
        int row = wr*64 + i*16 + hg*4 + rr;
        #pragma unroll
        for (int j = 0; j < 4; ++j)
          Xch[row*64 + j*16 + lid] = acc[i][j][rr];
      }
  }
  __syncthreads();
  if (wc == 1) {
    #pragma unroll
    for (int i = 0; i < 4; ++i)
      #pragma unroll
      for (int rr = 0; rr < 4; ++rr) {
        int row = wr*64 + i*16 + hg*4 + rr;
        int gr = bm + row;
        if (gr >= cnt) continue;
        u16* orow = hid + (size_t)(slot0 + row) * kHID + g*64;
        #pragma unroll
        for (int j = 0; j < 4; ++j) {
          int col = j*16 + lid;
          float g1 = Xch[row*64 + col];
          float g3 = acc[i][j][rr];
          orow[col] = f2bf(g1 / (1.f + __expf(-g1)) * g3);
        }
      }
  }
}

// ------- MoE down-proj: same fixed-T4 structure (stageA=4, loadB=16 -> same counts) -------
// grid (bn, tile): bn fastest -> same-w2-slice blocks 16 apart -> same XCD.
__global__ __launch_bounds__(256) void gemm_down_kernel(
    const u16* __restrict__ hid, const float* __restrict__ W2,
    u16* __restrict__ ff, const int* __restrict__ padbase,
    const int* __restrict__ tileTab) {
  int tab = tileTab[blockIdx.y];
  if (tab < 0) return;
  int e = tab >> 8, mb = tab & 255;
  int slot0 = padbase[e] + mb * 128;
  int bn = blockIdx.x * 128;
  __shared__ __align__(16) char SM[65536];
  u16* As[2] = { (u16*)SM, (u16*)(SM + 16384) };
  char* Bs[2] = { SM + 32768, SM + 49152 };
  int tid = threadIdx.x, lane = tid & 63, w = tid >> 6;
  int wr = w >> 1, wc = w & 1;
  int hg = lane >> 4, lid = lane & 15;
  f32x4 acc[4][4] = {};

  const u16* aP[4];
  #pragma unroll
  for (int j = 0; j < 4; ++j) {
    int r = w*32 + j*8 + (lane >> 3);
    int colc = ((lane & 7) ^ (r & 7)) * 8;
    aP[j] = hid + (size_t)(slot0 + r) * kHID + colc;
  }
  int c0 = (tid & 63) * 2, kgrp = tid >> 6;
  const float* b2e = W2 + (size_t)e*kHID*kD + (size_t)bn + c0;
  int wOffX[4], wOffY[4];
  #pragma unroll
  for (int q = 0; q < 4; ++q) {
    int k0b = (kgrp*16 + q*4) * 2;
    wOffX[q] = (c0*128 + k0b) ^ ((c0 & 7) << 4);
    wOffY[q] = ((c0+1)*128 + k0b) ^ (((c0+1) & 7) << 4);
  }
  float2 rE[16], rO[16];

  auto stageA = [&](int buf, int t) {   // 4 VMEM
    int kt = t * 64;
    #pragma unroll
    for (int j = 0; j < 4; ++j) gll16(aP[j] + kt, &As[buf][w*2048 + j*512]);
  };
  auto loadB = [&](float2* r, int t) {  // 16 VMEM
    int kt = t * 64;
    #pragma unroll
    for (int j = 0; j < 16; ++j)
      r[j] = *(const float2*)(b2e + (size_t)(kt + kgrp*16 + j) * kD);
  };
  auto writeB = [&](int buf, float2* r) {
    #pragma unroll
    for (int q = 0; q < 4; ++q) {
      *(u32x2*)(Bs[buf] + wOffX[q]) = pk4bf(r[q*4].x, r[q*4+1].x, r[q*4+2].x, r[q*4+3].x);
      *(u32x2*)(Bs[buf] + wOffY[q]) = pk4bf(r[q*4].y, r[q*4+1].y, r[q*4+2].y, r[q*4+3].y);
    }
  };
  auto compute = [&](int buf) {
    const char* AsB = (const char*)As[buf];
    const char* Bb = Bs[buf];
    #pragma unroll
    for (int kk = 0; kk < 2; ++kk) {
      bf16x8 af[4], bfv[4];
      #pragma unroll
      for (int f = 0; f < 4; ++f) {
        int rA = wr*64 + f*16 + lid;
        af[f] = *(const bf16x8*)(AsB + ((rA*128 + kk*64 + hg*16) ^ ((rA & 7) << 4)));
        int rB = wc*64 + f*16 + lid;
        bfv[f] = *(const bf16x8*)(Bb + ((rB*128 + kk*64 + hg*16) ^ ((rB & 7) << 4)));
      }
      __builtin_amdgcn_s_setprio(1);
      #pragma unroll
      for (int i = 0; i < 4; ++i)
        #pragma unroll
        for (int j = 0; j < 4; ++j)
          acc[i][j] = __builtin_amdgcn_mfma_f32_16x16x32_bf16(af[i], bfv[j], acc[i][j], 0, 0, 0);
      __builtin_amdgcn_s_setprio(0);
    }
  };

  constexpr int NT = kHID / 64;  // 64 (even)
  stageA(0, 0); stageA(1, 1);
  loadB(rE, 0);
  loadB(rO, 1);
  writeB(0, rE);
  barlgkm();
  for (int t = 0; t + 2 < NT; t += 2) {
    loadB(rE, t+2);
    compute(0);
    baronly();
    stageA(0, t+2);
    writeB(1, rO);
    barvm20();
    loadB(rO, t+3);
    compute(1);
    baronly();
    stageA(1, t+3);
    writeB(0, rE);
    barvm20();
  }
  compute(0);
  baronly();
  writeB(1, rO);
  barvm0();
  compute(1);
  __syncthreads();

  #pragma unroll
  for (int i = 0; i < 4; ++i)
    #pragma unroll
    for (int rr = 0; rr < 4; ++rr) {
      int row = wr*64 + i*16 + hg*4 + rr;
      u16* orow = ff + (size_t)(slot0 + row) * kD + bn;
      #pragma unroll
      for (int j = 0; j < 4; ++j)
        orow[wc*64 + j*16 + lid] = f2bf(acc[i][j][rr]);
    }
}

// ---------------- combine ----------------
__global__ __launch_bounds__(256) void moe_combine_kernel(
    const u16* __restrict__ ff, const int* __restrict__ padbase,
    const int* __restrict__ packA, const int* __restrict__ packB,
    const float* __restrict__ cA, const float* __restrict__ cB,
    float* __restrict__ outp) {
  int row = blockIdx.x, tid = threadIdx.x;
  int pa = packA[row], pb = packB[row];
  int sa = padbase[pa >> 11] + (pa & 2047);
  int sb = padbase[pb >> 11] + (pb & 2047);
  float ca = cA[row], cb = cB[row];
  union { int4 i4; u16 u[8]; } va, vb;
  va.i4 = *(const int4*)(ff + (size_t)sa * kD + tid*8);
  vb.i4 = *(const int4*)(ff + (size_t)sb * kD + tid*8);
  float* o = outp + (size_t)row * kD + tid*8;
  float4 o0 = *(const float4*)o;
  float4 o1 = *(const float4*)(o + 4);
  o0.x += ca*bf2f(va.u[0]) + cb*bf2f(vb.u[0]);
  o0.y += ca*bf2f(va.u[1]) + cb*bf2f(vb.u[1]);
  o0.z += ca*bf2f(va.u[2]) + cb*bf2f(vb.u[2]);
  o0.w += ca*bf2f(va.u[3]) + cb*bf2f(vb.u[3]);
  o1.x += ca*bf2f(va.u[4]) + cb*bf2f(vb.u[4]);
  o1.y += ca*bf2f(va.u[5]) + cb*bf2f(vb.u[5]);
  o1.z += ca*bf2f(va.u[6]) + cb*bf2f(vb.u[6]);
  o1.w += ca*bf2f(va.u[7]) + cb*bf2f(vb.u[7]);
  *(float4*)o = o0;
  *(float4*)(o + 4) = o1;
}

// ---------------- host launcher ----------------
extern "C" void kernel_launch(void* const* d_in, const int* in_sizes, int n_in,
                              void* d_out, int out_size, void* d_ws, size_t ws_size,
                              hipStream_t stream) {
  const float* x    = (const float*)d_in[0];
  const float* fcos = (const float*)d_in[1];
  const float* fsin = (const float*)d_in[2];
  const float* anw  = (const float*)d_in[5];
  const float* fnw  = (const float*)d_in[6];
  const float* wq   = (const float*)d_in[7];
  const float* wk   = (const float*)d_in[8];
  const float* wv   = (const float*)d_in[9];
  const float* wo   = (const float*)d_in[10];
  const float* gw   = (const float*)d_in[11];
  const float* w1   = (const float*)d_in[12];
  const float* w2   = (const float*)d_in[13];
  const float* w3   = (const float*)d_in[14];
  float* outp = (float*)d_out;

  char* ws = (char*)d_ws;
  size_t off = 0;
  auto alloc = [&](size_t bytes) -> void* {
    void* p = ws + off; off += (bytes + 255) & ~(size_t)255; return p;
  };
  f16* h16h   = (f16*)alloc((size_t)kRows*kD*2);
  f16* h16l   = (f16*)alloc((size_t)kRows*kD*2);
  float* qkv  = (float*)alloc((size_t)kRows*kQKVN*4);
  f16* Ksh    = (f16*)alloc((size_t)kB*kKVH*kS*kHD*2);
  f16* Ksl    = (f16*)alloc((size_t)kB*kKVH*kS*kHD*2);
  f16* vTh    = (f16*)alloc((size_t)kB*kKVH*kHD*kS*2);
  f16* vTl    = (f16*)alloc((size_t)kB*kKVH*kHD*kS*2);
  f16* a16h   = (f16*)alloc((size_t)kRows*kD*2);
  f16* a16l   = (f16*)alloc((size_t)kRows*kD*2);
  u16* tbf    = (u16*)alloc((size_t)kRows*kD*2);
  int* packA  = (int*)alloc(kRows*4);
  int* packB  = (int*)alloc(kRows*4);
  float* cAv  = (float*)alloc(kRows*4);
  float* cBv  = (float*)alloc(kRows*4);
  int* counts = (int*)alloc(kE*4);
  int* padbase= (int*)alloc(kE*4);
  int* tileTab= (int*)alloc(kMaxTiles*4);
  int* lists  = (int*)alloc((size_t)kE*kRows*4);
  f16* Bqh    = (f16*)alloc((size_t)kQKVN*kD*2);
  f16* Bql    = (f16*)alloc((size_t)kQKVN*kD*2);
  f16* Bwh    = (f16*)alloc((size_t)kD*kD*2);
  f16* Bwl    = (f16*)alloc((size_t)kD*kD*2);
  u16* hid    = (u16*)alloc((size_t)kSlotsPad*kHID*2);
  u16* ffb    = (u16*)alloc((size_t)kSlotsPad*kD*2);

  // ---- weight prep (qkv/wo only; MoE weights consumed in f32 directly) ----
  transpose_split_kernel<<<dim3(kD/32, kD/32), dim3(32,8), 0, stream>>>(wq, Bqh, Bql, kD, 2048, 0, kD);
  transpose_split_kernel<<<dim3(512/32, kD/32), dim3(32,8), 0, stream>>>(wk, Bqh, Bql, kD, 512, 2048, kD);
  transpose_split_kernel<<<dim3(512/32, kD/32), dim3(32,8), 0, stream>>>(wv, Bqh, Bql, kD, 512, 2560, kD);
  transpose_split_kernel<<<dim3(kD/32, kD/32), dim3(32,8), 0, stream>>>(wo, Bwh, Bwl, kD, kD, 0, kD);

  // ---- attention path (split-f16 MFMA, f32-equivalent precision) ----
  rms_split_kernel<<<kRows, 256, 0, stream>>>(x, anw, h16h, h16l);
  gemm_sf16_kernel<false><<<dim3(kQKVN/128, kRows/128), 256, 0, stream>>>(
      h16h, h16l, kD, Bqh, Bql, qkv, kQKVN, 0, nullptr, 0, kD);
  rope_kernel<<<(kB*kS*(kH+kKVH)*(kHD/2))/256, 256, 0, stream>>>(qkv, fcos, fsin, Ksh, Ksl);
  vt_split_kernel<<<dim3(kS/32, (kKVH*kHD)/32, kB), dim3(32,8), 0, stream>>>(qkv, vTh, vTl);
  attn_sf16_kernel<<<dim3(kS/64, kH, kB), 256, 0, stream>>>(qkv, Ksh, Ksl, vTh, vTl, a16h, a16l);
  gemm_sf16_kernel<true><<<dim3(kD/128, kRows/128), 256, 0, stream>>>(
      a16h, a16l, kD, Bwh, Bwl, outp, kD, 0, x, kD, kD);

  // ---- gate ----
  zero_counts_kernel<<<1, 64, 0, stream>>>(counts);
  gate_kernel<<<kRows, 64, 0, stream>>>(outp, fnw, gw, packA, packB, cAv, cBv, lists, counts);
  prefix_kernel<<<1, 64, 0, stream>>>(counts, padbase, tileTab);
  rms_bf16_kernel<<<kRows, 256, 0, stream>>>(outp, fnw, tbf);

  // ---- MoE: 2 batched GEMMs (direct f32 weights) + combine ----
  gemm_up_kernel<<<dim3(kHID/64, kMaxTiles), 256, 0, stream>>>(
      tbf, w1, w3, hid, lists, counts, padbase, tileTab);
  gemm_down_kernel<<<dim3(kD/128, kMaxTiles), 256, 0, stream>>>(
      hid, w2, ffb, padbase, tileTab);
  moe_combine_kernel<<<kRows, 256, 0, stream>>>(
      ffb, padbase, packA, packB, cAv, cBv, outp);
}

// Round 13
// 865.874 us; speedup vs baseline: 1.3100x; 1.3100x over previous
//
#include <hip/hip_runtime.h>

typedef unsigned short u16;
typedef unsigned int u32;
typedef __bf16 bf16x8 __attribute__((ext_vector_type(8)));
typedef _Float16 f16;
typedef f16 f16x8 __attribute__((ext_vector_type(8)));
typedef float f32x4 __attribute__((ext_vector_type(4)));
typedef u32 u32x2 __attribute__((ext_vector_type(2)));

#define DEVFN __device__ __forceinline__

constexpr int kB = 2, kS = 1024, kD = 2048, kH = 16, kKVH = 4, kHD = 128;
constexpr int kHID = 4096, kE = 8;
constexpr int kRows = kB * kS;               // 2048 tokens
constexpr int kQKVN = kH*kHD + 2*kKVH*kHD;   // 3072 fused qkv cols
constexpr int kSlotsPad = 5120;              // 40 tiles x 128
constexpr int kMaxTiles = 40;
constexpr float kEps = 1e-5f;
constexpr float kNeg = -1000000000.0f;
constexpr float kScale = 0.08838834764831845f;

DEVFN u16 f2bf(float f) {
  u32 u = __float_as_uint(f);
  return (u16)((u + 0x7fffu + ((u >> 16) & 1u)) >> 16);
}
DEVFN float bf2f(u16 u) { u32 v = ((u32)u) << 16; return __uint_as_float(v); }

DEVFN void split8v(float4 a, float4 b, f16x8& hi, f16x8& lo) {
  float v[8] = {a.x, a.y, a.z, a.w, b.x, b.y, b.z, b.w};
  #pragma unroll
  for (int e = 0; e < 8; ++e) {
    f16 h = (f16)v[e];
    hi[e] = h;
    lo[e] = (f16)(v[e] - (float)h);
  }
}

DEVFN void gll16(const void* g, void* l) {
  __builtin_amdgcn_global_load_lds(
      (const __attribute__((address_space(1))) void*)g,
      (__attribute__((address_space(3))) void*)l, 16, 0, 0);
}

// 4 f32 -> 4 bf16 (RNE, value-identical to f2bf) packed in 64 bits
DEVFN u32x2 pk4bf(float a, float b, float c, float d) {
  union { __bf16 h[4]; u32x2 w; } u;
  u.h[0] = (__bf16)a; u.h[1] = (__bf16)b;
  u.h[2] = (__bf16)c; u.h[3] = (__bf16)d;
  return u.w;
}

// ---------------- RMSNorm + f16 split ----------------
__global__ __launch_bounds__(256) void rms_split_kernel(const float* __restrict__ in,
    const float* __restrict__ w, f16* __restrict__ oh, f16* __restrict__ ol) {
  int row = blockIdx.x, tid = threadIdx.x;
  const float* x = in + (size_t)row * kD;
  float4 v0 = *(const float4*)&x[tid*8];
  float4 v1 = *(const float4*)&x[tid*8+4];
  float ss = v0.x*v0.x+v0.y*v0.y+v0.z*v0.z+v0.w*v0.w
           + v1.x*v1.x+v1.y*v1.y+v1.z*v1.z+v1.w*v1.w;
  #pragma unroll
  for (int off = 32; off; off >>= 1) ss += __shfl_xor(ss, off);
  __shared__ float red[4];
  if ((tid & 63) == 0) red[tid >> 6] = ss;
  __syncthreads();
  float tot = red[0] + red[1] + red[2] + red[3];
  float rs = rsqrtf(tot * (1.0f/kD) + kEps);
  float4 w0 = *(const float4*)&w[tid*8];
  float4 w1 = *(const float4*)&w[tid*8+4];
  float4 o0, o1;
  o0.x = v0.x*rs*w0.x; o0.y = v0.y*rs*w0.y; o0.z = v0.z*rs*w0.z; o0.w = v0.w*rs*w0.w;
  o1.x = v1.x*rs*w1.x; o1.y = v1.y*rs*w1.y; o1.z = v1.z*rs*w1.z; o1.w = v1.w*rs*w1.w;
  f16x8 hi, lo;
  split8v(o0, o1, hi, lo);
  *(f16x8*)&oh[(size_t)row*kD + tid*8] = hi;
  *(f16x8*)&ol[(size_t)row*kD + tid*8] = lo;
}

__global__ __launch_bounds__(256) void rms_bf16_kernel(const float* __restrict__ in,
    const float* __restrict__ w, u16* __restrict__ out) {
  int row = blockIdx.x, tid = threadIdx.x;
  const float* x = in + (size_t)row * kD;
  float4 v0 = *(const float4*)&x[tid*8];
  float4 v1 = *(const float4*)&x[tid*8+4];
  float ss = v0.x*v0.x+v0.y*v0.y+v0.z*v0.z+v0.w*v0.w
           + v1.x*v1.x+v1.y*v1.y+v1.z*v1.z+v1.w*v1.w;
  #pragma unroll
  for (int off = 32; off; off >>= 1) ss += __shfl_xor(ss, off);
  __shared__ float red[4];
  if ((tid & 63) == 0) red[tid >> 6] = ss;
  __syncthreads();
  float tot = red[0] + red[1] + red[2] + red[3];
  float rs = rsqrtf(tot * (1.0f/kD) + kEps);
  float4 w0 = *(const float4*)&w[tid*8];
  float4 w1 = *(const float4*)&w[tid*8+4];
  union { int4 i4; u16 u[8]; } pk;
  pk.u[0] = f2bf(v0.x*rs*w0.x); pk.u[1] = f2bf(v0.y*rs*w0.y);
  pk.u[2] = f2bf(v0.z*rs*w0.z); pk.u[3] = f2bf(v0.w*rs*w0.w);
  pk.u[4] = f2bf(v1.x*rs*w1.x); pk.u[5] = f2bf(v1.y*rs*w1.y);
  pk.u[6] = f2bf(v1.z*rs*w1.z); pk.u[7] = f2bf(v1.w*rs*w1.w);
  *(int4*)&out[(size_t)row*kD + tid*8] = pk.i4;
}

// ------- transpose + f16-split (qkv/wo weights): f32 [R][C] -> hi/lo [C+noff][R] -------
__global__ void transpose_split_kernel(const float* __restrict__ in,
    f16* __restrict__ hi, f16* __restrict__ lo, int R, int C, int noff, int ldout) {
  __shared__ float tile[32][33];
  int c0 = blockIdx.x * 32, r0 = blockIdx.y * 32;
  int tx = threadIdx.x, ty = threadIdx.y;
  #pragma unroll
  for (int i = 0; i < 32; i += 8)
    tile[ty + i][tx] = in[(size_t)(r0 + ty + i) * C + c0 + tx];
  __syncthreads();
  #pragma unroll
  for (int i = 0; i < 32; i += 8) {
    float v = tile[tx][ty + i];
    f16 h = (f16)v;
    size_t o = (size_t)(noff + c0 + ty + i) * ldout + r0 + tx;
    hi[o] = h;
    lo[o] = (f16)(v - (float)h);
  }
}

// ------- V transpose + split: qkv V cols -> vTh/vTl [b][kvh*128+d][S] f16 -------
__global__ void vt_split_kernel(const float* __restrict__ qkv,
    f16* __restrict__ vTh, f16* __restrict__ vTl) {
  __shared__ float tile[32][33];
  int s0 = blockIdx.x * 32, c0 = blockIdx.y * 32, b = blockIdx.z;
  int tx = threadIdx.x, ty = threadIdx.y;
  #pragma unroll
  for (int i = 0; i < 32; i += 8)
    tile[ty + i][tx] = qkv[(size_t)(b*kS + s0 + ty + i) * kQKVN + kH*kHD + kKVH*kHD + c0 + tx];
  __syncthreads();
  #pragma unroll
  for (int i = 0; i < 32; i += 8) {
    float v = tile[tx][ty + i];
    f16 h = (f16)v;
    size_t o = (size_t)(b*kKVH*kHD + c0 + ty + i) * kS + s0 + tx;
    vTh[o] = h;
    vTl[o] = (f16)(v - (float)h);
  }
}

// ---------------- split-f16 GEMM via global_load_lds ----------------
template<bool ADDX>
__global__ __launch_bounds__(256) void gemm_sf16_kernel(
    const f16* __restrict__ Ah0, const f16* __restrict__ Al0, int lda,
    const f16* __restrict__ Bh0, const f16* __restrict__ Bl0,
    float* __restrict__ C, int ldc, int coff,
    const float* __restrict__ X, int ldx, int K) {
  __shared__ __align__(16) u16 Ah[128*64], Al[128*64], Bh[128*64], Bl[128*64];
  int tid = threadIdx.x, lane = tid & 63, w = tid >> 6;
  int bm = blockIdx.y * 128, bn = blockIdx.x * 128;
  int wr = w >> 1, wc = w & 1;
  int hg = lane >> 4, lid = lane & 15;
  f32x4 acc[4][4] = {};
  const f16 *aH[4], *aL[4], *bH[4], *bL[4];
  #pragma unroll
  for (int j = 0; j < 4; ++j) {
    int r = w*32 + j*8 + (lane >> 3);
    int colc = ((lane & 7) ^ (r & 7)) * 8;
    aH[j] = Ah0 + (size_t)(bm + r) * lda + colc;
    aL[j] = Al0 + (size_t)(bm + r) * lda + colc;
    bH[j] = Bh0 + (size_t)(bn + r) * K + colc;
    bL[j] = Bl0 + (size_t)(bn + r) * K + colc;
  }
  const char* AhB = (const char*)Ah; const char* AlB = (const char*)Al;
  const char* BhB = (const char*)Bh; const char* BlB = (const char*)Bl;
  for (int kt = 0; kt < K; kt += 64) {
    __syncthreads();
    #pragma unroll
    for (int j = 0; j < 4; ++j) {
      int lb = w*2048 + j*512;
      gll16(aH[j] + kt, &Ah[lb]);
      gll16(aL[j] + kt, &Al[lb]);
      gll16(bH[j] + kt, &Bh[lb]);
      gll16(bL[j] + kt, &Bl[lb]);
    }
    __syncthreads();
    #pragma unroll
    for (int kk = 0; kk < 2; ++kk) {
      f16x8 ah[4], al[4], bh[4], bl[4];
      #pragma unroll
      for (int f = 0; f < 4; ++f) {
        int rA = wr*64 + f*16 + lid;
        int oA = (rA*128 + kk*64 + hg*16) ^ ((rA & 7) << 4);
        ah[f] = *(const f16x8*)(AhB + oA);
        al[f] = *(const f16x8*)(AlB + oA);
        int rB = wc*64 + f*16 + lid;
        int oB = (rB*128 + kk*64 + hg*16) ^ ((rB & 7) << 4);
        bh[f] = *(const f16x8*)(BhB + oB);
        bl[f] = *(const f16x8*)(BlB + oB);
      }
      __builtin_amdgcn_s_setprio(1);
      #pragma unroll
      for (int i = 0; i < 4; ++i)
        #pragma unroll
        for (int j = 0; j < 4; ++j) {
          acc[i][j] = __builtin_amdgcn_mfma_f32_16x16x32_f16(ah[i], bh[j], acc[i][j], 0, 0, 0);
          acc[i][j] = __builtin_amdgcn_mfma_f32_16x16x32_f16(ah[i], bl[j], acc[i][j], 0, 0, 0);
          acc[i][j] = __builtin_amdgcn_mfma_f32_16x16x32_f16(al[i], bh[j], acc[i][j], 0, 0, 0);
        }
      __builtin_amdgcn_s_setprio(0);
    }
  }
  #pragma unroll
  for (int i = 0; i < 4; ++i) {
    #pragma unroll
    for (int rr = 0; rr < 4; ++rr) {
      size_t gr = (size_t)(bm + wr*64 + i*16 + hg*4 + rr);
      #pragma unroll
      for (int j = 0; j < 4; ++j) {
        int gc = bn + wc*64 + j*16 + lid;
        float v = acc[i][j][rr];
        if (ADDX) v += X[gr * ldx + gc];
        C[gr * ldc + coff + gc] = v;
      }
    }
  }
}

// ---------------- RoPE: Q in-place, K -> pre-split f16 buffers ----------------
__global__ __launch_bounds__(256) void rope_kernel(float* __restrict__ qkv,
    const float* __restrict__ fc, const float* __restrict__ fs,
    f16* __restrict__ Kh, f16* __restrict__ Kl) {
  int idx = blockIdx.x * 256 + threadIdx.x;
  constexpr int NQ = kB*kS*kH*(kHD/2);
  constexpr int NK = kB*kS*kKVH*(kHD/2);
  if (idx < NQ) {
    int i = idx & 63, h = (idx >> 6) & 15, s = (idx >> 10) & 1023, b = idx >> 20;
    size_t base = ((size_t)(b*kS + s))*kQKVN + h*kHD + 2*i;
    float c = fc[s*64 + i], sn = fs[s*64 + i];
    float xr = qkv[base], xi = qkv[base+1];
    qkv[base]   = xr*c - xi*sn;
    qkv[base+1] = xr*sn + xi*c;
  } else {
    int j = idx - NQ; if (j >= NK) return;
    int i = j & 63, h = (j >> 6) & 3, s = (j >> 8) & 1023, b = j >> 18;
    size_t src = ((size_t)(b*kS + s))*kQKVN + kH*kHD + h*kHD + 2*i;
    float c = fc[s*64 + i], sn = fs[s*64 + i];
    float xr = qkv[src], xi = qkv[src+1];
    float o0 = xr*c - xi*sn, o1 = xr*sn + xi*c;
    size_t dst = (((size_t)(b*kKVH + h))*kS + s)*kHD + 2*i;
    f16 h0 = (f16)o0, h1 = (f16)o1;
    Kh[dst]   = h0; Kl[dst]   = (f16)(o0 - (float)h0);
    Kh[dst+1] = h1; Kl[dst+1] = (f16)(o1 - (float)h1);
  }
}

// ---------------- split-f16 MFMA flash attention (pre-split K/V) ----------------
// Epilogue emits split-f16 (a16h/a16l) directly -> feeds wo GEMM, no split pass.
__global__ __launch_bounds__(256) void attn_sf16_kernel(const float* __restrict__ qkv,
    const f16* __restrict__ Ksh, const f16* __restrict__ Ksl,
    const f16* __restrict__ vTh, const f16* __restrict__ vTl,
    f16* __restrict__ outh, f16* __restrict__ outl) {
  int qt = (int)gridDim.x - 1 - blockIdx.x;
  int h = blockIdx.y, b = blockIdx.z;
  int kvh = h >> 2;
  int q0 = qt * 64;
  __shared__ __align__(16) char Kh[64*128*2], Kl[64*128*2];
  __shared__ __align__(16) char Vh[128*64*2], Vl[128*64*2];
  __shared__ __align__(16) char Ph[4][16*64*2], Pl[4][16*64*2];
  int tid = threadIdx.x, lane = tid & 63, w = tid >> 6;
  int hg = lane >> 4, lid = lane & 15;

  f16x8 qh[4], ql[4];
  {
    const float* qrow = qkv + (size_t)(b*kS + q0 + w*16 + lid) * kQKVN + h*kHD;
    #pragma unroll
    for (int ks = 0; ks < 4; ++ks) {
      float4 a = *(const float4*)(qrow + ks*32 + hg*8);
      float4 c = *(const float4*)(qrow + ks*32 + hg*8 + 4);
      split8v(a, c, qh[ks], ql[ks]);
    }
  }
  f32x4 oacc[8] = {};
  float m[4] = {-3.0e38f, -3.0e38f, -3.0e38f, -3.0e38f};
  float lsum[4] = {};
  char* Phw = Ph[w];
  char* Plw = Pl[w];

  for (int kt = 0; kt <= qt; ++kt) {
    __syncthreads();
    {
      int r = tid >> 2, c0 = (tid & 3) * 32;
      const f16* khr = Ksh + ((size_t)(b*kKVH + kvh)*kS + kt*64 + r) * kHD + c0;
      const f16* klr = Ksl + ((size_t)(b*kKVH + kvh)*kS + kt*64 + r) * kHD + c0;
      #pragma unroll
      for (int s8 = 0; s8 < 4; ++s8) {
        int4 hi = *(const int4*)(khr + s8*8);
        int4 lo = *(const int4*)(klr + s8*8);
        int off = (r*256 + c0*2 + s8*16) ^ ((r & 7) << 4);
        *(int4*)(Kh + off) = hi;
        *(int4*)(Kl + off) = lo;
      }
    }
    {
      int r = tid >> 1, c0 = (tid & 1) * 32;
      const f16* vhr = vTh + (size_t)(b*kKVH*kHD + kvh*kHD + r) * kS + kt*64 + c0;
      const f16* vlr = vTl + (size_t)(b*kKVH*kHD + kvh*kHD + r) * kS + kt*64 + c0;
      #pragma unroll
      for (int s8 = 0; s8 < 4; ++s8) {
        int4 hi = *(const int4*)(vhr + s8*8);
        int4 lo = *(const int4*)(vlr + s8*8);
        int off = (r*128 + c0*2 + s8*16) ^ ((r & 7) << 4);
        *(int4*)(Vh + off) = hi;
        *(int4*)(Vl + off) = lo;
      }
    }
    __syncthreads();

    f32x4 sacc[4] = {};
    __builtin_amdgcn_s_setprio(1);
    #pragma unroll
    for (int ks = 0; ks < 4; ++ks) {
      #pragma unroll
      for (int j = 0; j < 4; ++j) {
        int rB = j*16 + lid;
        int off = (rB*256 + ks*64 + hg*16) ^ ((rB & 7) << 4);
        f16x8 kh = *(const f16x8*)(Kh + off);
        f16x8 klo = *(const f16x8*)(Kl + off);
        sacc[j] = __builtin_amdgcn_mfma_f32_16x16x32_f16(qh[ks], kh, sacc[j], 0, 0, 0);
        sacc[j] = __builtin_amdgcn_mfma_f32_16x16x32_f16(qh[ks], klo, sacc[j], 0, 0, 0);
        sacc[j] = __builtin_amdgcn_mfma_f32_16x16x32_f16(ql[ks], kh, sacc[j], 0, 0, 0);
      }
    }
    __builtin_amdgcn_s_setprio(0);
    float s[4][4], ps[4][4];
    bool diag = (kt == qt);
    #pragma unroll
    for (int j = 0; j < 4; ++j)
      #pragma unroll
      for (int r = 0; r < 4; ++r) {
        float v = sacc[j][r] * kScale;
        if (diag) {
          int kvabs = kt*64 + j*16 + lid;
          int qabs = q0 + w*16 + hg*4 + r;
          if (kvabs > qabs) v = kNeg;
        }
        s[j][r] = v;
      }
    float pm[4], cf[4];
    #pragma unroll
    for (int r = 0; r < 4; ++r) {
      pm[r] = fmaxf(fmaxf(s[0][r], s[1][r]), fmaxf(s[2][r], s[3][r]));
      #pragma unroll
      for (int msk = 1; msk < 16; msk <<= 1) pm[r] = fmaxf(pm[r], __shfl_xor(pm[r], msk));
      float mn = fmaxf(m[r], pm[r]);
      cf[r] = __expf(m[r] - mn);
      m[r] = mn;
    }
    #pragma unroll
    for (int j2 = 0; j2 < 8; ++j2)
      #pragma unroll
      for (int r = 0; r < 4; ++r) oacc[j2][r] *= cf[r];
    float rs[4] = {};
    #pragma unroll
    for (int j = 0; j < 4; ++j)
      #pragma unroll
      for (int r = 0; r < 4; ++r) {
        float p = __expf(s[j][r] - m[r]);
        ps[j][r] = p;
        rs[r] += p;
      }
    #pragma unroll
    for (int r = 0; r < 4; ++r) lsum[r] = lsum[r]*cf[r] + rs[r];
    #pragma unroll
    for (int j = 0; j < 4; ++j)
      #pragma unroll
      for (int r = 0; r < 4; ++r) {
        int q = hg*4 + r;
        int off = (q*128 + (j*16 + lid)*2) ^ ((q & 7) << 4);
        f16 ph = (f16)ps[j][r];
        *(f16*)(Phw + off) = ph;
        *(f16*)(Plw + off) = (f16)(ps[j][r] - (float)ph);
      }
    #pragma unroll
    for (int kk2 = 0; kk2 < 2; ++kk2) {
      int oP = (lid*128 + kk2*64 + hg*16) ^ ((lid & 7) << 4);
      f16x8 pa_h = *(const f16x8*)(Phw + oP);
      f16x8 pa_l = *(const f16x8*)(Plw + oP);
      __builtin_amdgcn_s_setprio(1);
      #pragma unroll
      for (int j2 = 0; j2 < 8; ++j2) {
        int rV = j2*16 + lid;
        int off = (rV*128 + kk2*64 + hg*16) ^ ((rV & 7) << 4);
        f16x8 vh = *(const f16x8*)(Vh + off);
        f16x8 vl = *(const f16x8*)(Vl + off);
        oacc[j2] = __builtin_amdgcn_mfma_f32_16x16x32_f16(pa_h, vh, oacc[j2], 0, 0, 0);
        oacc[j2] = __builtin_amdgcn_mfma_f32_16x16x32_f16(pa_h, vl, oacc[j2], 0, 0, 0);
        oacc[j2] = __builtin_amdgcn_mfma_f32_16x16x32_f16(pa_l, vh, oacc[j2], 0, 0, 0);
      }
      __builtin_amdgcn_s_setprio(0);
    }
  }
  #pragma unroll
  for (int r = 0; r < 4; ++r) {
    #pragma unroll
    for (int msk = 1; msk < 16; msk <<= 1) lsum[r] += __shfl_xor(lsum[r], msk);
    lsum[r] = 1.f / lsum[r];
  }
  #pragma unroll
  for (int j2 = 0; j2 < 8; ++j2)
    #pragma unroll
    for (int r = 0; r < 4; ++r) {
      size_t o = (size_t)(b*kS + q0 + w*16 + hg*4 + r) * kD + h*kHD + j2*16 + lid;
      float v = oacc[j2][r] * lsum[r];
      f16 hh = (f16)v;
      outh[o] = hh;
      outl[o] = (f16)(v - (float)hh);
    }
}

// ---------------- gate / prefix+table ----------------
__global__ void zero_counts_kernel(int* counts) {
  if (threadIdx.x < kE) counts[threadIdx.x] = 0;
}

__global__ __launch_bounds__(64) void gate_kernel(const float* __restrict__ h1,
    const float* __restrict__ wn, const float* __restrict__ gw,
    int* __restrict__ packA, int* __restrict__ packB,
    float* __restrict__ cA, float* __restrict__ cB,
    int* __restrict__ lists, int* __restrict__ counts) {
  int row = blockIdx.x, lane = threadIdx.x;
  const float* x = h1 + (size_t)row * kD;
  float ss = 0.f;
  for (int d = lane; d < kD; d += 64) { float v = x[d]; ss = fmaf(v, v, ss); }
  #pragma unroll
  for (int off = 32; off; off >>= 1) ss += __shfl_xor(ss, off);
  float rs = rsqrtf(ss * (1.0f/kD) + kEps);
  float acc[kE] = {};
  for (int d = lane; d < kD; d += 64) {
    float g = x[d] * rs * wn[d];
    const float* gr = gw + (size_t)d * kE;
    #pragma unroll
    for (int e = 0; e < kE; ++e) acc[e] = fmaf(g, gr[e], acc[e]);
  }
  #pragma unroll
  for (int e = 0; e < kE; ++e)
    #pragma unroll
    for (int off = 32; off; off >>= 1) acc[e] += __shfl_xor(acc[e], off);
  if (lane == 0) {
    int i1 = 0; float l1 = acc[0];
    #pragma unroll
    for (int e = 1; e < kE; ++e) if (acc[e] > l1) { l1 = acc[e]; i1 = e; }
    int i2 = -1; float l2 = -3.4e38f;
    #pragma unroll
    for (int e = 0; e < kE; ++e) if (e != i1 && acc[e] > l2) { l2 = acc[e]; i2 = e; }
    float e2 = __expf(l2 - l1);
    float inv = 1.f / (1.f + e2);
    int p1 = atomicAdd(&counts[i1], 1); lists[i1*kRows + p1] = row;
    int p2 = atomicAdd(&counts[i2], 1); lists[i2*kRows + p2] = row;
    packA[row] = i1*2048 + p1; cA[row] = inv;
    packB[row] = i2*2048 + p2; cB[row] = e2 * inv;
  }
}

__global__ void prefix_kernel(const int* __restrict__ counts,
    int* __restrict__ padbase, int* __restrict__ tileTab) {
  if (threadIdx.x == 0) {
    int base = 0, idx = 0;
    for (int e = 0; e < kE; ++e) {
      padbase[e] = base;
      int nt = (counts[e] + 127) >> 7;
      for (int t = 0; t < nt; ++t) tileTab[idx++] = (e << 8) | t;
      base += nt << 7;
    }
    for (; idx < kMaxTiles; ++idx) tileTab[idx] = -1;
  }
}

// ------- MoE up-proj (round-8 proven): BK=64, 64KB LDS, reg k-quad B staging -------
// grid (g, tile): g fastest -> same-B-slice blocks 64 apart -> same XCD.
__global__ __launch_bounds__(256) void gemm_up_kernel(
    const u16* __restrict__ A, const float* __restrict__ W1, const float* __restrict__ W3,
    u16* __restrict__ hid, const int* __restrict__ lists,
    const int* __restrict__ counts, const int* __restrict__ padbase,
    const int* __restrict__ tileTab) {
  int tab = tileTab[blockIdx.y];
  if (tab < 0) return;
  int e = tab >> 8, mb = tab & 255;
  int cnt = counts[e];
  int bm = mb * 128;
  int slot0 = padbase[e] + bm;
  const int* ids = lists + e * kRows;
  int g = blockIdx.x;
  __shared__ __align__(16) char SM[65536];
  u16* As[2]   = { (u16*)SM, (u16*)(SM + 16384) };
  char* B1s[2] = { SM + 32768, SM + 40960 };   // [64 n][128B] each
  char* B3s[2] = { SM + 49152, SM + 57344 };
  int tid = threadIdx.x, lane = tid & 63, w = tid >> 6;
  int wr = w >> 1, wc = w & 1;
  int hg = lane >> 4, lid = lane & 15;
  f32x4 acc[4][4] = {};

  const u16* aP[4];
  #pragma unroll
  for (int j = 0; j < 4; ++j) {
    int r = w*32 + j*8 + (lane >> 3);
    int colc = ((lane & 7) ^ (r & 7)) * 8;
    int rr = bm + r; if (rr >= cnt) rr = cnt - 1;
    aP[j] = A + (size_t)ids[rr] * kD + colc;
  }
  const float* b1e = W1 + (size_t)e*kD*kHID + (size_t)g*64 + lane;
  const float* b3e = W3 + (size_t)e*kD*kHID + (size_t)g*64 + lane;
  int wOff[4];
  #pragma unroll
  for (int s = 0; s < 4; ++s)
    wOff[s] = (lane*128 + s*32 + w*8) ^ ((lane & 7) << 4);

  auto stageA = [&](int buf, int t) {
    int kt = t * 64;
    #pragma unroll
    for (int j = 0; j < 4; ++j) gll16(aP[j] + kt, &As[buf][w*2048 + j*512]);
  };
  float r1v[4][4], r3v[4][4];
  auto loadB = [&](int t) {
    int kt = t * 64;
    #pragma unroll
    for (int s = 0; s < 4; ++s)
      #pragma unroll
      for (int j = 0; j < 4; ++j) {
        size_t ko = (size_t)(kt + s*16 + w*4 + j) * kHID;
        r1v[s][j] = b1e[ko];
        r3v[s][j] = b3e[ko];
      }
  };
  auto writeB = [&](int buf) {
    #pragma unroll
    for (int s = 0; s < 4; ++s) {
      *(u32x2*)(B1s[buf] + wOff[s]) = pk4bf(r1v[s][0], r1v[s][1], r1v[s][2], r1v[s][3]);
      *(u32x2*)(B3s[buf] + wOff[s]) = pk4bf(r3v[s][0], r3v[s][1], r3v[s][2], r3v[s][3]);
    }
  };
  auto compute = [&](int buf) {
    const char* AsB = (const char*)As[buf];
    const char* Bb = wc ? B3s[buf] : B1s[buf];
    #pragma unroll
    for (int kk = 0; kk < 2; ++kk) {
      bf16x8 af[4], bfv[4];
      #pragma unroll
      for (int f = 0; f < 4; ++f) {
        int rA = wr*64 + f*16 + lid;
        af[f] = *(const bf16x8*)(AsB + ((rA*128 + kk*64 + hg*16) ^ ((rA & 7) << 4)));
        int rB = f*16 + lid;
        bfv[f] = *(const bf16x8*)(Bb + ((rB*128 + kk*64 + hg*16) ^ ((rB & 7) << 4)));
      }
      __builtin_amdgcn_s_setprio(1);
      #pragma unroll
      for (int i = 0; i < 4; ++i)
        #pragma unroll
        for (int j = 0; j < 4; ++j)
          acc[i][j] = __builtin_amdgcn_mfma_f32_16x16x32_bf16(af[i], bfv[j], acc[i][j], 0, 0, 0);
      __builtin_amdgcn_s_setprio(0);
    }
  };

  constexpr int NT = kD / 64;  // 32
  stageA(0, 0);
  loadB(0);
  writeB(0);
  __syncthreads();
  for (int t = 0; t < NT; t += 2) {
    stageA(1, t+1); loadB(t+1);
    compute(0);
    writeB(1);
    __syncthreads();
    if (t+2 < NT) { stageA(0, t+2); loadB(t+2); }
    compute(1);
    if (t+2 < NT) writeB(0);
    __syncthreads();
  }

  float* Xch = (float*)SM;
  if (wc == 0) {
    #pragma unroll
    for (int i = 0; i < 4; ++i)
      #pragma unroll
      for (int rr = 0; rr < 4; ++rr) {
        int row = wr*64 + i*16 + hg*4 + rr;
        #pragma unroll
        for (int j = 0; j < 4; ++j)
          Xch[row*64 + j*16 + lid] = acc[i][j][rr];
      }
  }
  __syncthreads();
  if (wc == 1) {
    #pragma unroll
    for (int i = 0; i < 4; ++i)
      #pragma unroll
      for (int rr = 0; rr < 4; ++rr) {
        int row = wr*64 + i*16 + hg*4 + rr;
        int gr = bm + row;
        if (gr >= cnt) continue;
        u16* orow = hid + (size_t)(slot0 + row) * kHID + g*64;
        #pragma unroll
        for (int j = 0; j < 4; ++j) {
          int col = j*16 + lid;
          float g1 = Xch[row*64 + col];
          float g3 = acc[i][j][rr];
          orow[col] = f2bf(g1 / (1.f + __expf(-g1)) * g3);
        }
      }
  }
}

// ------- MoE down-proj (round-8 proven) -------
// grid (bn, tile): bn fastest -> same-w2-slice blocks 16 apart -> same XCD.
__global__ __launch_bounds__(256) void gemm_down_kernel(
    const u16* __restrict__ hid, const float* __restrict__ W2,
    u16* __restrict__ ff, const int* __restrict__ padbase,
    const int* __restrict__ tileTab) {
  int tab = tileTab[blockIdx.y];
  if (tab < 0) return;
  int e = tab >> 8, mb = tab & 255;
  int slot0 = padbase[e] + mb * 128;
  int bn = blockIdx.x * 128;
  __shared__ __align__(16) char SM[65536];
  u16* As[2] = { (u16*)SM, (u16*)(SM + 16384) };
  char* Bs[2] = { SM + 32768, SM + 49152 };    // [128 n][128B] each
  int tid = threadIdx.x, lane = tid & 63, w = tid >> 6;
  int wr = w >> 1, wc = w & 1;
  int hg = lane >> 4, lid = lane & 15;
  f32x4 acc[4][4] = {};

  const u16* aP[4];
  #pragma unroll
  for (int j = 0; j < 4; ++j) {
    int r = w*32 + j*8 + (lane >> 3);
    int colc = ((lane & 7) ^ (r & 7)) * 8;
    aP[j] = hid + (size_t)(slot0 + r) * kHID + colc;
  }
  int nrow = (w & 1)*64 + lane;
  int kq = w >> 1;
  const float* b2e = W2 + (size_t)e*kHID*kD + (size_t)bn + nrow;
  int wOff[8];
  #pragma unroll
  for (int s = 0; s < 8; ++s)
    wOff[s] = (nrow*128 + s*16 + kq*8) ^ ((nrow & 7) << 4);

  auto stageA = [&](int buf, int t) {
    int kt = t * 64;
    #pragma unroll
    for (int j = 0; j < 4; ++j) gll16(aP[j] + kt, &As[buf][w*2048 + j*512]);
  };
  float rbv[8][4];
  auto loadB = [&](int t) {
    int kt = t * 64;
    #pragma unroll
    for (int s = 0; s < 8; ++s)
      #pragma unroll
      for (int j = 0; j < 4; ++j)
        rbv[s][j] = b2e[(size_t)(kt + s*8 + kq*4 + j) * kD];
  };
  auto writeB = [&](int buf) {
    #pragma unroll
    for (int s = 0; s < 8; ++s)
      *(u32x2*)(Bs[buf] + wOff[s]) = pk4bf(rbv[s][0], rbv[s][1], rbv[s][2], rbv[s][3]);
  };
  auto compute = [&](int buf) {
    const char* AsB = (const char*)As[buf];
    const char* Bb = Bs[buf];
    #pragma unroll
    for (int kk = 0; kk < 2; ++kk) {
      bf16x8 af[4], bfv[4];
      #pragma unroll
      for (int f = 0; f < 4; ++f) {
        int rA = wr*64 + f*16 + lid;
        af[f] = *(const bf16x8*)(AsB + ((rA*128 + kk*64 + hg*16) ^ ((rA & 7) << 4)));
        int rB = wc*64 + f*16 + lid;
        bfv[f] = *(const bf16x8*)(Bb + ((rB*128 + kk*64 + hg*16) ^ ((rB & 7) << 4)));
      }
      __builtin_amdgcn_s_setprio(1);
      #pragma unroll
      for (int i = 0; i < 4; ++i)
        #pragma unroll
        for (int j = 0; j < 4; ++j)
          acc[i][j] = __builtin_amdgcn_mfma_f32_16x16x32_bf16(af[i], bfv[j], acc[i][j], 0, 0, 0);
      __builtin_amdgcn_s_setprio(0);
    }
  };

  constexpr int NT = kHID / 64;  // 64
  stageA(0, 0);
  loadB(0);
  writeB(0);
  __syncthreads();
  for (int t = 0; t < NT; t += 2) {
    stageA(1, t+1); loadB(t+1);
    compute(0);
    writeB(1);
    __syncthreads();
    if (t+2 < NT) { stageA(0, t+2); loadB(t+2); }
    compute(1);
    if (t+2 < NT) writeB(0);
    __syncthreads();
  }

  #pragma unroll
  for (int i = 0; i < 4; ++i)
    #pragma unroll
    for (int rr = 0; rr < 4; ++rr) {
      int row = wr*64 + i*16 + hg*4 + rr;
      u16* orow = ff + (size_t)(slot0 + row) * kD + bn;
      #pragma unroll
      for (int j = 0; j < 4; ++j)
        orow[wc*64 + j*16 + lid] = f2bf(acc[i][j][rr]);
    }
}

// ---------------- combine ----------------
__global__ __launch_bounds__(256) void moe_combine_kernel(
    const u16* __restrict__ ff, const int* __restrict__ padbase,
    const int* __restrict__ packA, const int* __restrict__ packB,
    const float* __restrict__ cA, const float* __restrict__ cB,
    float* __restrict__ outp) {
  int row = blockIdx.x, tid = threadIdx.x;
  int pa = packA[row], pb = packB[row];
  int sa = padbase[pa >> 11] + (pa & 2047);
  int sb = padbase[pb >> 11] + (pb & 2047);
  float ca = cA[row], cb = cB[row];
  union { int4 i4; u16 u[8]; } va, vb;
  va.i4 = *(const int4*)(ff + (size_t)sa * kD + tid*8);
  vb.i4 = *(const int4*)(ff + (size_t)sb * kD + tid*8);
  float* o = outp + (size_t)row * kD + tid*8;
  float4 o0 = *(const float4*)o;
  float4 o1 = *(const float4*)(o + 4);
  o0.x += ca*bf2f(va.u[0]) + cb*bf2f(vb.u[0]);
  o0.y += ca*bf2f(va.u[1]) + cb*bf2f(vb.u[1]);
  o0.z += ca*bf2f(va.u[2]) + cb*bf2f(vb.u[2]);
  o0.w += ca*bf2f(va.u[3]) + cb*bf2f(vb.u[3]);
  o1.x += ca*bf2f(va.u[4]) + cb*bf2f(vb.u[4]);
  o1.y += ca*bf2f(va.u[5]) + cb*bf2f(vb.u[5]);
  o1.z += ca*bf2f(va.u[6]) + cb*bf2f(vb.u[6]);
  o1.w += ca*bf2f(va.u[7]) + cb*bf2f(vb.u[7]);
  *(float4*)o = o0;
  *(float4*)(o + 4) = o1;
}

// ---------------- host launcher ----------------
extern "C" void kernel_launch(void* const* d_in, const int* in_sizes, int n_in,
                              void* d_out, int out_size, void* d_ws, size_t ws_size,
                              hipStream_t stream) {
  const float* x    = (const float*)d_in[0];
  const float* fcos = (const float*)d_in[1];
  const float* fsin = (const float*)d_in[2];
  const float* anw  = (const float*)d_in[5];
  const float* fnw  = (const float*)d_in[6];
  const float* wq   = (const float*)d_in[7];
  const float* wk   = (const float*)d_in[8];
  const float* wv   = (const float*)d_in[9];
  const float* wo   = (const float*)d_in[10];
  const float* gw   = (const float*)d_in[11];
  const float* w1   = (const float*)d_in[12];
  const float* w2   = (const float*)d_in[13];
  const float* w3   = (const float*)d_in[14];
  float* outp = (float*)d_out;

  char* ws = (char*)d_ws;
  size_t off = 0;
  auto alloc = [&](size_t bytes) -> void* {
    void* p = ws + off; off += (bytes + 255) & ~(size_t)255; return p;
  };
  f16* h16h   = (f16*)alloc((size_t)kRows*kD*2);
  f16* h16l   = (f16*)alloc((size_t)kRows*kD*2);
  float* qkv  = (float*)alloc((size_t)kRows*kQKVN*4);
  f16* Ksh    = (f16*)alloc((size_t)kB*kKVH*kS*kHD*2);
  f16* Ksl    = (f16*)alloc((size_t)kB*kKVH*kS*kHD*2);
  f16* vTh    = (f16*)alloc((size_t)kB*kKVH*kHD*kS*2);
  f16* vTl    = (f16*)alloc((size_t)kB*kKVH*kHD*kS*2);
  f16* a16h   = (f16*)alloc((size_t)kRows*kD*2);
  f16* a16l   = (f16*)alloc((size_t)kRows*kD*2);
  u16* tbf    = (u16*)alloc((size_t)kRows*kD*2);
  int* packA  = (int*)alloc(kRows*4);
  int* packB  = (int*)alloc(kRows*4);
  float* cAv  = (float*)alloc(kRows*4);
  float* cBv  = (float*)alloc(kRows*4);
  int* counts = (int*)alloc(kE*4);
  int* padbase= (int*)alloc(kE*4);
  int* tileTab= (int*)alloc(kMaxTiles*4);
  int* lists  = (int*)alloc((size_t)kE*kRows*4);
  f16* Bqh    = (f16*)alloc((size_t)kQKVN*kD*2);
  f16* Bql    = (f16*)alloc((size_t)kQKVN*kD*2);
  f16* Bwh    = (f16*)alloc((size_t)kD*kD*2);
  f16* Bwl    = (f16*)alloc((size_t)kD*kD*2);
  u16* hid    = (u16*)alloc((size_t)kSlotsPad*kHID*2);
  u16* ffb    = (u16*)alloc((size_t)kSlotsPad*kD*2);

  // ---- weight prep (qkv/wo only; MoE weights consumed in f32 directly) ----
  transpose_split_kernel<<<dim3(kD/32, kD/32), dim3(32,8), 0, stream>>>(wq, Bqh, Bql, kD, 2048, 0, kD);
  transpose_split_kernel<<<dim3(512/32, kD/32), dim3(32,8), 0, stream>>>(wk, Bqh, Bql, kD, 512, 2048, kD);
  transpose_split_kernel<<<dim3(512/32, kD/32), dim3(32,8), 0, stream>>>(wv, Bqh, Bql, kD, 512, 2560, kD);
  transpose_split_kernel<<<dim3(kD/32, kD/32), dim3(32,8), 0, stream>>>(wo, Bwh, Bwl, kD, kD, 0, kD);

  // ---- attention path (split-f16 MFMA, f32-equivalent precision) ----
  rms_split_kernel<<<kRows, 256, 0, stream>>>(x, anw, h16h, h16l);
  gemm_sf16_kernel<false><<<dim3(kQKVN/128, kRows/128), 256, 0, stream>>>(
      h16h, h16l, kD, Bqh, Bql, qkv, kQKVN, 0, nullptr, 0, kD);
  rope_kernel<<<(kB*kS*(kH+kKVH)*(kHD/2))/256, 256, 0, stream>>>(qkv, fcos, fsin, Ksh, Ksl);
  vt_split_kernel<<<dim3(kS/32, (kKVH*kHD)/32, kB), dim3(32,8), 0, stream>>>(qkv, vTh, vTl);
  attn_sf16_kernel<<<dim3(kS/64, kH, kB), 256, 0, stream>>>(qkv, Ksh, Ksl, vTh, vTl, a16h, a16l);
  gemm_sf16_kernel<true><<<dim3(kD/128, kRows/128), 256, 0, stream>>>(
      a16h, a16l, kD, Bwh, Bwl, outp, kD, 0, x, kD, kD);

  // ---- gate ----
  zero_counts_kernel<<<1, 64, 0, stream>>>(counts);
  gate_kernel<<<kRows, 64, 0, stream>>>(outp, fnw, gw, packA, packB, cAv, cBv, lists, counts);
  prefix_kernel<<<1, 64, 0, stream>>>(counts, padbase, tileTab);
  rms_bf16_kernel<<<kRows, 256, 0, stream>>>(outp, fnw, tbf);

  // ---- MoE: 2 batched GEMMs (direct f32 weights) + combine ----
  gemm_up_kernel<<<dim3(kHID/64, kMaxTiles), 256, 0, stream>>>(
      tbf, w1, w3, hid, lists, counts, padbase, tileTab);
  gemm_down_kernel<<<dim3(kD/128, kMaxTiles), 256, 0, stream>>>(
      hid, w2, ffb, padbase, tileTab);
  moe_combine_kernel<<<kRows, 256, 0, stream>>>(
      ffb, padbase, packA, packB, cAv, cBv, outp);
}

// Round 14
// 863.400 us; speedup vs baseline: 1.3138x; 1.0029x over previous
//
#include <hip/hip_runtime.h>

typedef unsigned short u16;
typedef unsigned int u32;
typedef __bf16 bf16x8 __attribute__((ext_vector_type(8)));
typedef _Float16 f16;
typedef f16 f16x8 __attribute__((ext_vector_type(8)));
typedef float f32x4 __attribute__((ext_vector_type(4)));
typedef u32 u32x2 __attribute__((ext_vector_type(2)));

#define DEVFN __device__ __forceinline__

constexpr int kB = 2, kS = 1024, kD = 2048, kH = 16, kKVH = 4, kHD = 128;
constexpr int kHID = 4096, kE = 8;
constexpr int kRows = kB * kS;               // 2048 tokens
constexpr int kQKVN = kH*kHD + 2*kKVH*kHD;   // 3072 fused qkv cols
constexpr int kSlotsPad = 5120;              // 40 tiles x 128
constexpr int kMaxTiles = 40;
constexpr float kEps = 1e-5f;
constexpr float kNeg = -1000000000.0f;
constexpr float kScale = 0.08838834764831845f;

DEVFN u16 f2bf(float f) {
  u32 u = __float_as_uint(f);
  return (u16)((u + 0x7fffu + ((u >> 16) & 1u)) >> 16);
}
DEVFN float bf2f(u16 u) { u32 v = ((u32)u) << 16; return __uint_as_float(v); }

DEVFN void split8v(float4 a, float4 b, f16x8& hi, f16x8& lo) {
  float v[8] = {a.x, a.y, a.z, a.w, b.x, b.y, b.z, b.w};
  #pragma unroll
  for (int e = 0; e < 8; ++e) {
    f16 h = (f16)v[e];
    hi[e] = h;
    lo[e] = (f16)(v[e] - (float)h);
  }
}

DEVFN void gll16(const void* g, void* l) {
  __builtin_amdgcn_global_load_lds(
      (const __attribute__((address_space(1))) void*)g,
      (__attribute__((address_space(3))) void*)l, 16, 0, 0);
}

// 4 f32 -> 4 bf16 (RNE, value-identical to f2bf) packed in 64 bits
DEVFN u32x2 pk4bf(float a, float b, float c, float d) {
  union { __bf16 h[4]; u32x2 w; } u;
  u.h[0] = (__bf16)a; u.h[1] = (__bf16)b;
  u.h[2] = (__bf16)c; u.h[3] = (__bf16)d;
  return u.w;
}

// ---------------- RMSNorm + f16 split ----------------
__global__ __launch_bounds__(256) void rms_split_kernel(const float* __restrict__ in,
    const float* __restrict__ w, f16* __restrict__ oh, f16* __restrict__ ol) {
  int row = blockIdx.x, tid = threadIdx.x;
  const float* x = in + (size_t)row * kD;
  float4 v0 = *(const float4*)&x[tid*8];
  float4 v1 = *(const float4*)&x[tid*8+4];
  float ss = v0.x*v0.x+v0.y*v0.y+v0.z*v0.z+v0.w*v0.w
           + v1.x*v1.x+v1.y*v1.y+v1.z*v1.z+v1.w*v1.w;
  #pragma unroll
  for (int off = 32; off; off >>= 1) ss += __shfl_xor(ss, off);
  __shared__ float red[4];
  if ((tid & 63) == 0) red[tid >> 6] = ss;
  __syncthreads();
  float tot = red[0] + red[1] + red[2] + red[3];
  float rs = rsqrtf(tot * (1.0f/kD) + kEps);
  float4 w0 = *(const float4*)&w[tid*8];
  float4 w1 = *(const float4*)&w[tid*8+4];
  float4 o0, o1;
  o0.x = v0.x*rs*w0.x; o0.y = v0.y*rs*w0.y; o0.z = v0.z*rs*w0.z; o0.w = v0.w*rs*w0.w;
  o1.x = v1.x*rs*w1.x; o1.y = v1.y*rs*w1.y; o1.z = v1.z*rs*w1.z; o1.w = v1.w*rs*w1.w;
  f16x8 hi, lo;
  split8v(o0, o1, hi, lo);
  *(f16x8*)&oh[(size_t)row*kD + tid*8] = hi;
  *(f16x8*)&ol[(size_t)row*kD + tid*8] = lo;
}

__global__ __launch_bounds__(256) void rms_bf16_kernel(const float* __restrict__ in,
    const float* __restrict__ w, u16* __restrict__ out) {
  int row = blockIdx.x, tid = threadIdx.x;
  const float* x = in + (size_t)row * kD;
  float4 v0 = *(const float4*)&x[tid*8];
  float4 v1 = *(const float4*)&x[tid*8+4];
  float ss = v0.x*v0.x+v0.y*v0.y+v0.z*v0.z+v0.w*v0.w
           + v1.x*v1.x+v1.y*v1.y+v1.z*v1.z+v1.w*v1.w;
  #pragma unroll
  for (int off = 32; off; off >>= 1) ss += __shfl_xor(ss, off);
  __shared__ float red[4];
  if ((tid & 63) == 0) red[tid >> 6] = ss;
  __syncthreads();
  float tot = red[0] + red[1] + red[2] + red[3];
  float rs = rsqrtf(tot * (1.0f/kD) + kEps);
  float4 w0 = *(const float4*)&w[tid*8];
  float4 w1 = *(const float4*)&w[tid*8+4];
  union { int4 i4; u16 u[8]; } pk;
  pk.u[0] = f2bf(v0.x*rs*w0.x); pk.u[1] = f2bf(v0.y*rs*w0.y);
  pk.u[2] = f2bf(v0.z*rs*w0.z); pk.u[3] = f2bf(v0.w*rs*w0.w);
  pk.u[4] = f2bf(v1.x*rs*w1.x); pk.u[5] = f2bf(v1.y*rs*w1.y);
  pk.u[6] = f2bf(v1.z*rs*w1.z); pk.u[7] = f2bf(v1.w*rs*w1.w);
  *(int4*)&out[(size_t)row*kD + tid*8] = pk.i4;
}

// ------- transpose + f16-split (qkv/wo weights): f32 [R][C] -> hi/lo [C+noff][R] -------
__global__ void transpose_split_kernel(const float* __restrict__ in,
    f16* __restrict__ hi, f16* __restrict__ lo, int R, int C, int noff, int ldout) {
  __shared__ float tile[32][33];
  int c0 = blockIdx.x * 32, r0 = blockIdx.y * 32;
  int tx = threadIdx.x, ty = threadIdx.y;
  #pragma unroll
  for (int i = 0; i < 32; i += 8)
    tile[ty + i][tx] = in[(size_t)(r0 + ty + i) * C + c0 + tx];
  __syncthreads();
  #pragma unroll
  for (int i = 0; i < 32; i += 8) {
    float v = tile[tx][ty + i];
    f16 h = (f16)v;
    size_t o = (size_t)(noff + c0 + ty + i) * ldout + r0 + tx;
    hi[o] = h;
    lo[o] = (f16)(v - (float)h);
  }
}

// ------- V transpose + split: qkv V cols -> vTh/vTl [b][kvh*128+d][S] f16 -------
__global__ void vt_split_kernel(const float* __restrict__ qkv,
    f16* __restrict__ vTh, f16* __restrict__ vTl) {
  __shared__ float tile[32][33];
  int s0 = blockIdx.x * 32, c0 = blockIdx.y * 32, b = blockIdx.z;
  int tx = threadIdx.x, ty = threadIdx.y;
  #pragma unroll
  for (int i = 0; i < 32; i += 8)
    tile[ty + i][tx] = qkv[(size_t)(b*kS + s0 + ty + i) * kQKVN + kH*kHD + kKVH*kHD + c0 + tx];
  __syncthreads();
  #pragma unroll
  for (int i = 0; i < 32; i += 8) {
    float v = tile[tx][ty + i];
    f16 h = (f16)v;
    size_t o = (size_t)(b*kKVH*kHD + c0 + ty + i) * kS + s0 + tx;
    vTh[o] = h;
    vTl[o] = (f16)(v - (float)h);
  }
}

// ---------------- split-f16 GEMM via global_load_lds ----------------
template<bool ADDX>
__global__ __launch_bounds__(256) void gemm_sf16_kernel(
    const f16* __restrict__ Ah0, const f16* __restrict__ Al0, int lda,
    const f16* __restrict__ Bh0, const f16* __restrict__ Bl0,
    float* __restrict__ C, int ldc, int coff,
    const float* __restrict__ X, int ldx, int K) {
  __shared__ __align__(16) u16 Ah[128*64], Al[128*64], Bh[128*64], Bl[128*64];
  int tid = threadIdx.x, lane = tid & 63, w = tid >> 6;
  int bm = blockIdx.y * 128, bn = blockIdx.x * 128;
  int wr = w >> 1, wc = w & 1;
  int hg = lane >> 4, lid = lane & 15;
  f32x4 acc[4][4] = {};
  const f16 *aH[4], *aL[4], *bH[4], *bL[4];
  #pragma unroll
  for (int j = 0; j < 4; ++j) {
    int r = w*32 + j*8 + (lane >> 3);
    int colc = ((lane & 7) ^ (r & 7)) * 8;
    aH[j] = Ah0 + (size_t)(bm + r) * lda + colc;
    aL[j] = Al0 + (size_t)(bm + r) * lda + colc;
    bH[j] = Bh0 + (size_t)(bn + r) * K + colc;
    bL[j] = Bl0 + (size_t)(bn + r) * K + colc;
  }
  const char* AhB = (const char*)Ah; const char* AlB = (const char*)Al;
  const char* BhB = (const char*)Bh; const char* BlB = (const char*)Bl;
  for (int kt = 0; kt < K; kt += 64) {
    __syncthreads();
    #pragma unroll
    for (int j = 0; j < 4; ++j) {
      int lb = w*2048 + j*512;
      gll16(aH[j] + kt, &Ah[lb]);
      gll16(aL[j] + kt, &Al[lb]);
      gll16(bH[j] + kt, &Bh[lb]);
      gll16(bL[j] + kt, &Bl[lb]);
    }
    __syncthreads();
    #pragma unroll
    for (int kk = 0; kk < 2; ++kk) {
      f16x8 ah[4], al[4], bh[4], bl[4];
      #pragma unroll
      for (int f = 0; f < 4; ++f) {
        int rA = wr*64 + f*16 + lid;
        int oA = (rA*128 + kk*64 + hg*16) ^ ((rA & 7) << 4);
        ah[f] = *(const f16x8*)(AhB + oA);
        al[f] = *(const f16x8*)(AlB + oA);
        int rB = wc*64 + f*16 + lid;
        int oB = (rB*128 + kk*64 + hg*16) ^ ((rB & 7) << 4);
        bh[f] = *(const f16x8*)(BhB + oB);
        bl[f] = *(const f16x8*)(BlB + oB);
      }
      __builtin_amdgcn_s_setprio(1);
      #pragma unroll
      for (int i = 0; i < 4; ++i)
        #pragma unroll
        for (int j = 0; j < 4; ++j) {
          acc[i][j] = __builtin_amdgcn_mfma_f32_16x16x32_f16(ah[i], bh[j], acc[i][j], 0, 0, 0);
          acc[i][j] = __builtin_amdgcn_mfma_f32_16x16x32_f16(ah[i], bl[j], acc[i][j], 0, 0, 0);
          acc[i][j] = __builtin_amdgcn_mfma_f32_16x16x32_f16(al[i], bh[j], acc[i][j], 0, 0, 0);
        }
      __builtin_amdgcn_s_setprio(0);
    }
  }
  #pragma unroll
  for (int i = 0; i < 4; ++i) {
    #pragma unroll
    for (int rr = 0; rr < 4; ++rr) {
      size_t gr = (size_t)(bm + wr*64 + i*16 + hg*4 + rr);
      #pragma unroll
      for (int j = 0; j < 4; ++j) {
        int gc = bn + wc*64 + j*16 + lid;
        float v = acc[i][j][rr];
        if (ADDX) v += X[gr * ldx + gc];
        C[gr * ldc + coff + gc] = v;
      }
    }
  }
}

// ---------------- RoPE: Q in-place, K -> pre-split f16 buffers ----------------
__global__ __launch_bounds__(256) void rope_kernel(float* __restrict__ qkv,
    const float* __restrict__ fc, const float* __restrict__ fs,
    f16* __restrict__ Kh, f16* __restrict__ Kl) {
  int idx = blockIdx.x * 256 + threadIdx.x;
  constexpr int NQ = kB*kS*kH*(kHD/2);
  constexpr int NK = kB*kS*kKVH*(kHD/2);
  if (idx < NQ) {
    int i = idx & 63, h = (idx >> 6) & 15, s = (idx >> 10) & 1023, b = idx >> 20;
    size_t base = ((size_t)(b*kS + s))*kQKVN + h*kHD + 2*i;
    float c = fc[s*64 + i], sn = fs[s*64 + i];
    float xr = qkv[base], xi = qkv[base+1];
    qkv[base]   = xr*c - xi*sn;
    qkv[base+1] = xr*sn + xi*c;
  } else {
    int j = idx - NQ; if (j >= NK) return;
    int i = j & 63, h = (j >> 6) & 3, s = (j >> 8) & 1023, b = j >> 18;
    size_t src = ((size_t)(b*kS + s))*kQKVN + kH*kHD + h*kHD + 2*i;
    float c = fc[s*64 + i], sn = fs[s*64 + i];
    float xr = qkv[src], xi = qkv[src+1];
    float o0 = xr*c - xi*sn, o1 = xr*sn + xi*c;
    size_t dst = (((size_t)(b*kKVH + h))*kS + s)*kHD + 2*i;
    f16 h0 = (f16)o0, h1 = (f16)o1;
    Kh[dst]   = h0; Kl[dst]   = (f16)(o0 - (float)h0);
    Kh[dst+1] = h1; Kl[dst+1] = (f16)(o1 - (float)h1);
  }
}

// ---------------- split-f16 MFMA flash attention (pre-split K/V) ----------------
// Epilogue emits split-f16 (a16h/a16l) directly -> feeds wo GEMM, no split pass.
__global__ __launch_bounds__(256) void attn_sf16_kernel(const float* __restrict__ qkv,
    const f16* __restrict__ Ksh, const f16* __restrict__ Ksl,
    const f16* __restrict__ vTh, const f16* __restrict__ vTl,
    f16* __restrict__ outh, f16* __restrict__ outl) {
  int qt = (int)gridDim.x - 1 - blockIdx.x;
  int h = blockIdx.y, b = blockIdx.z;
  int kvh = h >> 2;
  int q0 = qt * 64;
  __shared__ __align__(16) char Kh[64*128*2], Kl[64*128*2];
  __shared__ __align__(16) char Vh[128*64*2], Vl[128*64*2];
  __shared__ __align__(16) char Ph[4][16*64*2], Pl[4][16*64*2];
  int tid = threadIdx.x, lane = tid & 63, w = tid >> 6;
  int hg = lane >> 4, lid = lane & 15;

  f16x8 qh[4], ql[4];
  {
    const float* qrow = qkv + (size_t)(b*kS + q0 + w*16 + lid) * kQKVN + h*kHD;
    #pragma unroll
    for (int ks = 0; ks < 4; ++ks) {
      float4 a = *(const float4*)(qrow + ks*32 + hg*8);
      float4 c = *(const float4*)(qrow + ks*32 + hg*8 + 4);
      split8v(a, c, qh[ks], ql[ks]);
    }
  }
  f32x4 oacc[8] = {};
  float m[4] = {-3.0e38f, -3.0e38f, -3.0e38f, -3.0e38f};
  float lsum[4] = {};
  char* Phw = Ph[w];
  char* Plw = Pl[w];

  for (int kt = 0; kt <= qt; ++kt) {
    __syncthreads();
    {
      int r = tid >> 2, c0 = (tid & 3) * 32;
      const f16* khr = Ksh + ((size_t)(b*kKVH + kvh)*kS + kt*64 + r) * kHD + c0;
      const f16* klr = Ksl + ((size_t)(b*kKVH + kvh)*kS + kt*64 + r) * kHD + c0;
      #pragma unroll
      for (int s8 = 0; s8 < 4; ++s8) {
        int4 hi = *(const int4*)(khr + s8*8);
        int4 lo = *(const int4*)(klr + s8*8);
        int off = (r*256 + c0*2 + s8*16) ^ ((r & 7) << 4);
        *(int4*)(Kh + off) = hi;
        *(int4*)(Kl + off) = lo;
      }
    }
    {
      int r = tid >> 1, c0 = (tid & 1) * 32;
      const f16* vhr = vTh + (size_t)(b*kKVH*kHD + kvh*kHD + r) * kS + kt*64 + c0;
      const f16* vlr = vTl + (size_t)(b*kKVH*kHD + kvh*kHD + r) * kS + kt*64 + c0;
      #pragma unroll
      for (int s8 = 0; s8 < 4; ++s8) {
        int4 hi = *(const int4*)(vhr + s8*8);
        int4 lo = *(const int4*)(vlr + s8*8);
        int off = (r*128 + c0*2 + s8*16) ^ ((r & 7) << 4);
        *(int4*)(Vh + off) = hi;
        *(int4*)(Vl + off) = lo;
      }
    }
    __syncthreads();

    f32x4 sacc[4] = {};
    __builtin_amdgcn_s_setprio(1);
    #pragma unroll
    for (int ks = 0; ks < 4; ++ks) {
      #pragma unroll
      for (int j = 0; j < 4; ++j) {
        int rB = j*16 + lid;
        int off = (rB*256 + ks*64 + hg*16) ^ ((rB & 7) << 4);
        f16x8 kh = *(const f16x8*)(Kh + off);
        f16x8 klo = *(const f16x8*)(Kl + off);
        sacc[j] = __builtin_amdgcn_mfma_f32_16x16x32_f16(qh[ks], kh, sacc[j], 0, 0, 0);
        sacc[j] = __builtin_amdgcn_mfma_f32_16x16x32_f16(qh[ks], klo, sacc[j], 0, 0, 0);
        sacc[j] = __builtin_amdgcn_mfma_f32_16x16x32_f16(ql[ks], kh, sacc[j], 0, 0, 0);
      }
    }
    __builtin_amdgcn_s_setprio(0);
    float s[4][4], ps[4][4];
    bool diag = (kt == qt);
    #pragma unroll
    for (int j = 0; j < 4; ++j)
      #pragma unroll
      for (int r = 0; r < 4; ++r) {
        float v = sacc[j][r] * kScale;
        if (diag) {
          int kvabs = kt*64 + j*16 + lid;
          int qabs = q0 + w*16 + hg*4 + r;
          if (kvabs > qabs) v = kNeg;
        }
        s[j][r] = v;
      }
    float pm[4], cf[4];
    #pragma unroll
    for (int r = 0; r < 4; ++r) {
      pm[r] = fmaxf(fmaxf(s[0][r], s[1][r]), fmaxf(s[2][r], s[3][r]));
      #pragma unroll
      for (int msk = 1; msk < 16; msk <<= 1) pm[r] = fmaxf(pm[r], __shfl_xor(pm[r], msk));
      float mn = fmaxf(m[r], pm[r]);
      cf[r] = __expf(m[r] - mn);
      m[r] = mn;
    }
    #pragma unroll
    for (int j2 = 0; j2 < 8; ++j2)
      #pragma unroll
      for (int r = 0; r < 4; ++r) oacc[j2][r] *= cf[r];
    float rs[4] = {};
    #pragma unroll
    for (int j = 0; j < 4; ++j)
      #pragma unroll
      for (int r = 0; r < 4; ++r) {
        float p = __expf(s[j][r] - m[r]);
        ps[j][r] = p;
        rs[r] += p;
      }
    #pragma unroll
    for (int r = 0; r < 4; ++r) lsum[r] = lsum[r]*cf[r] + rs[r];
    #pragma unroll
    for (int j = 0; j < 4; ++j)
      #pragma unroll
      for (int r = 0; r < 4; ++r) {
        int q = hg*4 + r;
        int off = (q*128 + (j*16 + lid)*2) ^ ((q & 7) << 4);
        f16 ph = (f16)ps[j][r];
        *(f16*)(Phw + off) = ph;
        *(f16*)(Plw + off) = (f16)(ps[j][r] - (float)ph);
      }
    #pragma unroll
    for (int kk2 = 0; kk2 < 2; ++kk2) {
      int oP = (lid*128 + kk2*64 + hg*16) ^ ((lid & 7) << 4);
      f16x8 pa_h = *(const f16x8*)(Phw + oP);
      f16x8 pa_l = *(const f16x8*)(Plw + oP);
      __builtin_amdgcn_s_setprio(1);
      #pragma unroll
      for (int j2 = 0; j2 < 8; ++j2) {
        int rV = j2*16 + lid;
        int off = (rV*128 + kk2*64 + hg*16) ^ ((rV & 7) << 4);
        f16x8 vh = *(const f16x8*)(Vh + off);
        f16x8 vl = *(const f16x8*)(Vl + off);
        oacc[j2] = __builtin_amdgcn_mfma_f32_16x16x32_f16(pa_h, vh, oacc[j2], 0, 0, 0);
        oacc[j2] = __builtin_amdgcn_mfma_f32_16x16x32_f16(pa_h, vl, oacc[j2], 0, 0, 0);
        oacc[j2] = __builtin_amdgcn_mfma_f32_16x16x32_f16(pa_l, vh, oacc[j2], 0, 0, 0);
      }
      __builtin_amdgcn_s_setprio(0);
    }
  }
  #pragma unroll
  for (int r = 0; r < 4; ++r) {
    #pragma unroll
    for (int msk = 1; msk < 16; msk <<= 1) lsum[r] += __shfl_xor(lsum[r], msk);
    lsum[r] = 1.f / lsum[r];
  }
  #pragma unroll
  for (int j2 = 0; j2 < 8; ++j2)
    #pragma unroll
    for (int r = 0; r < 4; ++r) {
      size_t o = (size_t)(b*kS + q0 + w*16 + hg*4 + r) * kD + h*kHD + j2*16 + lid;
      float v = oacc[j2][r] * lsum[r];
      f16 hh = (f16)v;
      outh[o] = hh;
      outl[o] = (f16)(v - (float)hh);
    }
}

// ---------------- gate / prefix+table ----------------
__global__ void zero_counts_kernel(int* counts) {
  if (threadIdx.x < kE) counts[threadIdx.x] = 0;
}

__global__ __launch_bounds__(64) void gate_kernel(const float* __restrict__ h1,
    const float* __restrict__ wn, const float* __restrict__ gw,
    int* __restrict__ packA, int* __restrict__ packB,
    float* __restrict__ cA, float* __restrict__ cB,
    int* __restrict__ lists, int* __restrict__ counts) {
  int row = blockIdx.x, lane = threadIdx.x;
  const float* x = h1 + (size_t)row * kD;
  float ss = 0.f;
  for (int d = lane; d < kD; d += 64) { float v = x[d]; ss = fmaf(v, v, ss); }
  #pragma unroll
  for (int off = 32; off; off >>= 1) ss += __shfl_xor(ss, off);
  float rs = rsqrtf(ss * (1.0f/kD) + kEps);
  float acc[kE] = {};
  for (int d = lane; d < kD; d += 64) {
    float g = x[d] * rs * wn[d];
    const float* gr = gw + (size_t)d * kE;
    #pragma unroll
    for (int e = 0; e < kE; ++e) acc[e] = fmaf(g, gr[e], acc[e]);
  }
  #pragma unroll
  for (int e = 0; e < kE; ++e)
    #pragma unroll
    for (int off = 32; off; off >>= 1) acc[e] += __shfl_xor(acc[e], off);
  if (lane == 0) {
    int i1 = 0; float l1 = acc[0];
    #pragma unroll
    for (int e = 1; e < kE; ++e) if (acc[e] > l1) { l1 = acc[e]; i1 = e; }
    int i2 = -1; float l2 = -3.4e38f;
    #pragma unroll
    for (int e = 0; e < kE; ++e) if (e != i1 && acc[e] > l2) { l2 = acc[e]; i2 = e; }
    float e2 = __expf(l2 - l1);
    float inv = 1.f / (1.f + e2);
    int p1 = atomicAdd(&counts[i1], 1); lists[i1*kRows + p1] = row;
    int p2 = atomicAdd(&counts[i2], 1); lists[i2*kRows + p2] = row;
    packA[row] = i1*2048 + p1; cA[row] = inv;
    packB[row] = i2*2048 + p2; cB[row] = e2 * inv;
  }
}

__global__ void prefix_kernel(const int* __restrict__ counts,
    int* __restrict__ padbase, int* __restrict__ tileTab) {
  if (threadIdx.x == 0) {
    int base = 0, idx = 0;
    for (int e = 0; e < kE; ++e) {
      padbase[e] = base;
      int nt = (counts[e] + 127) >> 7;
      for (int t = 0; t < nt; ++t) tileTab[idx++] = (e << 8) | t;
      base += nt << 7;
    }
    for (; idx < kMaxTiles; ++idx) tileTab[idx] = -1;
  }
}

// ------- MoE up-proj: 8-wave (512 thr) blocks, acc[4][2]=32 AGPR/wave -------
// Same 128x(64|64) tile, LDS layout & math bit-identical to r8/r10; wave split:
// wr=w>>2 (row 64-half), wcc=w&3: wcc>>1 selects g1/g3, wcc&1 selects col 32-half.
// grid (g, tile): g fastest -> same-B-slice blocks 64 apart -> same XCD.
__global__ __launch_bounds__(512, 4) void gemm_up_kernel(
    const u16* __restrict__ A, const float* __restrict__ W1, const float* __restrict__ W3,
    u16* __restrict__ hid, const int* __restrict__ lists,
    const int* __restrict__ counts, const int* __restrict__ padbase,
    const int* __restrict__ tileTab) {
  int tab = tileTab[blockIdx.y];
  if (tab < 0) return;
  int e = tab >> 8, mb = tab & 255;
  int cnt = counts[e];
  int bm = mb * 128;
  int slot0 = padbase[e] + bm;
  const int* ids = lists + e * kRows;
  int g = blockIdx.x;
  __shared__ __align__(16) char SM[65536];
  u16* As[2]   = { (u16*)SM, (u16*)(SM + 16384) };
  char* B1s[2] = { SM + 32768, SM + 40960 };   // [64 n][128B] each
  char* B3s[2] = { SM + 49152, SM + 57344 };
  int tid = threadIdx.x, lane = tid & 63, w = tid >> 6;   // w in 0..7
  int wr = w >> 2, wcc = w & 3;
  int hg = lane >> 4, lid = lane & 15;
  f32x4 acc[4][2] = {};

  // A staging: 2 gll16 per thread (8 waves cover 128 rows)
  const u16* aP[2];
  #pragma unroll
  for (int j = 0; j < 2; ++j) {
    int r = w*16 + j*8 + (lane >> 3);
    int colc = ((lane & 7) ^ (r & 7)) * 8;
    int rr = bm + r; if (rr >= cnt) rr = cnt - 1;
    aP[j] = A + (size_t)ids[rr] * kD + colc;
  }
  // B: thread covers column n=lane; k's = w*8 + s*4 + j (8 per thread per matrix)
  const float* b1e = W1 + (size_t)e*kD*kHID + (size_t)g*64 + lane;
  const float* b3e = W3 + (size_t)e*kD*kHID + (size_t)g*64 + lane;
  int wOff[2];
  #pragma unroll
  for (int s = 0; s < 2; ++s)
    wOff[s] = (lane*128 + w*16 + s*8) ^ ((lane & 7) << 4);

  auto stageA = [&](int buf, int t) {
    int kt = t * 64;
    #pragma unroll
    for (int j = 0; j < 2; ++j) gll16(aP[j] + kt, &As[buf][w*1024 + j*512]);
  };
  float r1v[2][4], r3v[2][4];
  auto loadB = [&](int t) {
    int kt = t * 64;
    #pragma unroll
    for (int s = 0; s < 2; ++s)
      #pragma unroll
      for (int j = 0; j < 4; ++j) {
        size_t ko = (size_t)(kt + w*8 + s*4 + j) * kHID;
        r1v[s][j] = b1e[ko];
        r3v[s][j] = b3e[ko];
      }
  };
  auto writeB = [&](int buf) {
    #pragma unroll
    for (int s = 0; s < 2; ++s) {
      *(u32x2*)(B1s[buf] + wOff[s]) = pk4bf(r1v[s][0], r1v[s][1], r1v[s][2], r1v[s][3]);
      *(u32x2*)(B3s[buf] + wOff[s]) = pk4bf(r3v[s][0], r3v[s][1], r3v[s][2], r3v[s][3]);
    }
  };
  auto compute = [&](int buf) {
    const char* AsB = (const char*)As[buf];
    const char* Bb = (wcc >= 2) ? B3s[buf] : B1s[buf];
    #pragma unroll
    for (int kk = 0; kk < 2; ++kk) {
      bf16x8 af[4], bfv[2];
      #pragma unroll
      for (int f = 0; f < 4; ++f) {
        int rA = wr*64 + f*16 + lid;
        af[f] = *(const bf16x8*)(AsB + ((rA*128 + kk*64 + hg*16) ^ ((rA & 7) << 4)));
      }
      #pragma unroll
      for (int f = 0; f < 2; ++f) {
        int rB = (wcc & 1)*32 + f*16 + lid;
        bfv[f] = *(const bf16x8*)(Bb + ((rB*128 + kk*64 + hg*16) ^ ((rB & 7) << 4)));
      }
      __builtin_amdgcn_s_setprio(1);
      #pragma unroll
      for (int i = 0; i < 4; ++i)
        #pragma unroll
        for (int j = 0; j < 2; ++j)
          acc[i][j] = __builtin_amdgcn_mfma_f32_16x16x32_bf16(af[i], bfv[j], acc[i][j], 0, 0, 0);
      __builtin_amdgcn_s_setprio(0);
    }
  };

  constexpr int NT = kD / 64;  // 32
  stageA(0, 0);
  loadB(0);
  writeB(0);
  __syncthreads();
  for (int t = 0; t < NT; t += 2) {
    stageA(1, t+1); loadB(t+1);
    compute(0);
    writeB(1);
    __syncthreads();
    if (t+2 < NT) { stageA(0, t+2); loadB(t+2); }
    compute(1);
    if (t+2 < NT) writeB(0);
    __syncthreads();
  }

  // epilogue: g1 waves (wcc<2) -> Xch; g3 waves (wcc>=2) apply silu and store
  float* Xch = (float*)SM;
  if (wcc < 2) {
    #pragma unroll
    for (int i = 0; i < 4; ++i)
      #pragma unroll
      for (int rr = 0; rr < 4; ++rr) {
        int row = wr*64 + i*16 + hg*4 + rr;
        #pragma unroll
        for (int j = 0; j < 2; ++j)
          Xch[row*64 + (wcc & 1)*32 + j*16 + lid] = acc[i][j][rr];
      }
  }
  __syncthreads();
  if (wcc >= 2) {
    #pragma unroll
    for (int i = 0; i < 4; ++i)
      #pragma unroll
      for (int rr = 0; rr < 4; ++rr) {
        int row = wr*64 + i*16 + hg*4 + rr;
        int gr = bm + row;
        if (gr >= cnt) continue;
        u16* orow = hid + (size_t)(slot0 + row) * kHID + g*64 + (wcc & 1)*32;
        #pragma unroll
        for (int j = 0; j < 2; ++j) {
          int col = j*16 + lid;
          float g1 = Xch[row*64 + (wcc & 1)*32 + col];
          float g3 = acc[i][j][rr];
          orow[col] = f2bf(g1 / (1.f + __expf(-g1)) * g3);
        }
      }
  }
}

// ------- MoE down-proj: 8-wave (512 thr), acc[4][2]; same LDS/layout as r8 -------
// grid (bn, tile): bn fastest -> same-w2-slice blocks 16 apart -> same XCD.
__global__ __launch_bounds__(512, 4) void gemm_down_kernel(
    const u16* __restrict__ hid, const float* __restrict__ W2,
    u16* __restrict__ ff, const int* __restrict__ padbase,
    const int* __restrict__ tileTab) {
  int tab = tileTab[blockIdx.y];
  if (tab < 0) return;
  int e = tab >> 8, mb = tab & 255;
  int slot0 = padbase[e] + mb * 128;
  int bn = blockIdx.x * 128;
  __shared__ __align__(16) char SM[65536];
  u16* As[2] = { (u16*)SM, (u16*)(SM + 16384) };
  char* Bs[2] = { SM + 32768, SM + 49152 };    // [128 n][128B] each
  int tid = threadIdx.x, lane = tid & 63, w = tid >> 6;   // 0..7
  int wr = w >> 2, wc = w & 3;
  int hg = lane >> 4, lid = lane & 15;
  f32x4 acc[4][2] = {};

  const u16* aP[2];
  #pragma unroll
  for (int j = 0; j < 2; ++j) {
    int r = w*16 + j*8 + (lane >> 3);
    int colc = ((lane & 7) ^ (r & 7)) * 8;
    aP[j] = hid + (size_t)(slot0 + r) * kHID + colc;
  }
  // B: thread covers column n = tid&127; k-quad group kq = tid>>7 (0..3)
  int nrow = tid & 127;
  int kq = tid >> 7;
  const float* b2e = W2 + (size_t)e*kHID*kD + (size_t)bn + nrow;
  int wOff[4];
  #pragma unroll
  for (int s = 0; s < 4; ++s)
    wOff[s] = (nrow*128 + kq*32 + s*8) ^ ((nrow & 7) << 4);

  auto stageA = [&](int buf, int t) {
    int kt = t * 64;
    #pragma unroll
    for (int j = 0; j < 2; ++j) gll16(aP[j] + kt, &As[buf][w*1024 + j*512]);
  };
  float rbv[4][4];
  auto loadB = [&](int t) {
    int kt = t * 64;
    #pragma unroll
    for (int s = 0; s < 4; ++s)
      #pragma unroll
      for (int j = 0; j < 4; ++j)
        rbv[s][j] = b2e[(size_t)(kt + kq*16 + s*4 + j) * kD];
  };
  auto writeB = [&](int buf) {
    #pragma unroll
    for (int s = 0; s < 4; ++s)
      *(u32x2*)(Bs[buf] + wOff[s]) = pk4bf(rbv[s][0], rbv[s][1], rbv[s][2], rbv[s][3]);
  };
  auto compute = [&](int buf) {
    const char* AsB = (const char*)As[buf];
    const char* Bb = Bs[buf];
    #pragma unroll
    for (int kk = 0; kk < 2; ++kk) {
      bf16x8 af[4], bfv[2];
      #pragma unroll
      for (int f = 0; f < 4; ++f) {
        int rA = wr*64 + f*16 + lid;
        af[f] = *(const bf16x8*)(AsB + ((rA*128 + kk*64 + hg*16) ^ ((rA & 7) << 4)));
      }
      #pragma unroll
      for (int f = 0; f < 2; ++f) {
        int rB = wc*32 + f*16 + lid;
        bfv[f] = *(const bf16x8*)(Bb + ((rB*128 + kk*64 + hg*16) ^ ((rB & 7) << 4)));
      }
      __builtin_amdgcn_s_setprio(1);
      #pragma unroll
      for (int i = 0; i < 4; ++i)
        #pragma unroll
        for (int j = 0; j < 2; ++j)
          acc[i][j] = __builtin_amdgcn_mfma_f32_16x16x32_bf16(af[i], bfv[j], acc[i][j], 0, 0, 0);
      __builtin_amdgcn_s_setprio(0);
    }
  };

  constexpr int NT = kHID / 64;  // 64
  stageA(0, 0);
  loadB(0);
  writeB(0);
  __syncthreads();
  for (int t = 0; t < NT; t += 2) {
    stageA(1, t+1); loadB(t+1);
    compute(0);
    writeB(1);
    __syncthreads();
    if (t+2 < NT) { stageA(0, t+2); loadB(t+2); }
    compute(1);
    if (t+2 < NT) writeB(0);
    __syncthreads();
  }

  #pragma unroll
  for (int i = 0; i < 4; ++i)
    #pragma unroll
    for (int rr = 0; rr < 4; ++rr) {
      int row = wr*64 + i*16 + hg*4 + rr;
      u16* orow = ff + (size_t)(slot0 + row) * kD + bn;
      #pragma unroll
      for (int j = 0; j < 2; ++j)
        orow[wc*32 + j*16 + lid] = f2bf(acc[i][j][rr]);
    }
}

// ---------------- combine ----------------
__global__ __launch_bounds__(256) void moe_combine_kernel(
    const u16* __restrict__ ff, const int* __restrict__ padbase,
    const int* __restrict__ packA, const int* __restrict__ packB,
    const float* __restrict__ cA, const float* __restrict__ cB,
    float* __restrict__ outp) {
  int row = blockIdx.x, tid = threadIdx.x;
  int pa = packA[row], pb = packB[row];
  int sa = padbase[pa >> 11] + (pa & 2047);
  int sb = padbase[pb >> 11] + (pb & 2047);
  float ca = cA[row], cb = cB[row];
  union { int4 i4; u16 u[8]; } va, vb;
  va.i4 = *(const int4*)(ff + (size_t)sa * kD + tid*8);
  vb.i4 = *(const int4*)(ff + (size_t)sb * kD + tid*8);
  float* o = outp + (size_t)row * kD + tid*8;
  float4 o0 = *(const float4*)o;
  float4 o1 = *(const float4*)(o + 4);
  o0.x += ca*bf2f(va.u[0]) + cb*bf2f(vb.u[0]);
  o0.y += ca*bf2f(va.u[1]) + cb*bf2f(vb.u[1]);
  o0.z += ca*bf2f(va.u[2]) + cb*bf2f(vb.u[2]);
  o0.w += ca*bf2f(va.u[3]) + cb*bf2f(vb.u[3]);
  o1.x += ca*bf2f(va.u[4]) + cb*bf2f(vb.u[4]);
  o1.y += ca*bf2f(va.u[5]) + cb*bf2f(vb.u[5]);
  o1.z += ca*bf2f(va.u[6]) + cb*bf2f(vb.u[6]);
  o1.w += ca*bf2f(va.u[7]) + cb*bf2f(vb.u[7]);
  *(float4*)o = o0;
  *(float4*)(o + 4) = o1;
}

// ---------------- host launcher ----------------
extern "C" void kernel_launch(void* const* d_in, const int* in_sizes, int n_in,
                              void* d_out, int out_size, void* d_ws, size_t ws_size,
                              hipStream_t stream) {
  const float* x    = (const float*)d_in[0];
  const float* fcos = (const float*)d_in[1];
  const float* fsin = (const float*)d_in[2];
  const float* anw  = (const float*)d_in[5];
  const float* fnw  = (const float*)d_in[6];
  const float* wq   = (const float*)d_in[7];
  const float* wk   = (const float*)d_in[8];
  const float* wv   = (const float*)d_in[9];
  const float* wo   = (const float*)d_in[10];
  const float* gw   = (const float*)d_in[11];
  const float* w1   = (const float*)d_in[12];
  const float* w2   = (const float*)d_in[13];
  const float* w3   = (const float*)d_in[14];
  float* outp = (float*)d_out;

  char* ws = (char*)d_ws;
  size_t off = 0;
  auto alloc = [&](size_t bytes) -> void* {
    void* p = ws + off; off += (bytes + 255) & ~(size_t)255; return p;
  };
  f16* h16h   = (f16*)alloc((size_t)kRows*kD*2);
  f16* h16l   = (f16*)alloc((size_t)kRows*kD*2);
  float* qkv  = (float*)alloc((size_t)kRows*kQKVN*4);
  f16* Ksh    = (f16*)alloc((size_t)kB*kKVH*kS*kHD*2);
  f16* Ksl    = (f16*)alloc((size_t)kB*kKVH*kS*kHD*2);
  f16* vTh    = (f16*)alloc((size_t)kB*kKVH*kHD*kS*2);
  f16* vTl    = (f16*)alloc((size_t)kB*kKVH*kHD*kS*2);
  f16* a16h   = (f16*)alloc((size_t)kRows*kD*2);
  f16* a16l   = (f16*)alloc((size_t)kRows*kD*2);
  u16* tbf    = (u16*)alloc((size_t)kRows*kD*2);
  int* packA  = (int*)alloc(kRows*4);
  int* packB  = (int*)alloc(kRows*4);
  float* cAv  = (float*)alloc(kRows*4);
  float* cBv  = (float*)alloc(kRows*4);
  int* counts = (int*)alloc(kE*4);
  int* padbase= (int*)alloc(kE*4);
  int* tileTab= (int*)alloc(kMaxTiles*4);
  int* lists  = (int*)alloc((size_t)kE*kRows*4);
  f16* Bqh    = (f16*)alloc((size_t)kQKVN*kD*2);
  f16* Bql    = (f16*)alloc((size_t)kQKVN*kD*2);
  f16* Bwh    = (f16*)alloc((size_t)kD*kD*2);
  f16* Bwl    = (f16*)alloc((size_t)kD*kD*2);
  u16* hid    = (u16*)alloc((size_t)kSlotsPad*kHID*2);
  u16* ffb    = (u16*)alloc((size_t)kSlotsPad*kD*2);

  // ---- weight prep (qkv/wo only; MoE weights consumed in f32 directly) ----
  transpose_split_kernel<<<dim3(kD/32, kD/32), dim3(32,8), 0, stream>>>(wq, Bqh, Bql, kD, 2048, 0, kD);
  transpose_split_kernel<<<dim3(512/32, kD/32), dim3(32,8), 0, stream>>>(wk, Bqh, Bql, kD, 512, 2048, kD);
  transpose_split_kernel<<<dim3(512/32, kD/32), dim3(32,8), 0, stream>>>(wv, Bqh, Bql, kD, 512, 2560, kD);
  transpose_split_kernel<<<dim3(kD/32, kD/32), dim3(32,8), 0, stream>>>(wo, Bwh, Bwl, kD, kD, 0, kD);

  // ---- attention path (split-f16 MFMA, f32-equivalent precision) ----
  rms_split_kernel<<<kRows, 256, 0, stream>>>(x, anw, h16h, h16l);
  gemm_sf16_kernel<false><<<dim3(kQKVN/128, kRows/128), 256, 0, stream>>>(
      h16h, h16l, kD, Bqh, Bql, qkv, kQKVN, 0, nullptr, 0, kD);
  rope_kernel<<<(kB*kS*(kH+kKVH)*(kHD/2))/256, 256, 0, stream>>>(qkv, fcos, fsin, Ksh, Ksl);
  vt_split_kernel<<<dim3(kS/32, (kKVH*kHD)/32, kB), dim3(32,8), 0, stream>>>(qkv, vTh, vTl);
  attn_sf16_kernel<<<dim3(kS/64, kH, kB), 256, 0, stream>>>(qkv, Ksh, Ksl, vTh, vTl, a16h, a16l);
  gemm_sf16_kernel<true><<<dim3(kD/128, kRows/128), 256, 0, stream>>>(
      a16h, a16l, kD, Bwh, Bwl, outp, kD, 0, x, kD, kD);

  // ---- gate ----
  zero_counts_kernel<<<1, 64, 0, stream>>>(counts);
  gate_kernel<<<kRows, 64, 0, stream>>>(outp, fnw, gw, packA, packB, cAv, cBv, lists, counts);
  prefix_kernel<<<1, 64, 0, stream>>>(counts, padbase, tileTab);
  rms_bf16_kernel<<<kRows, 256, 0, stream>>>(outp, fnw, tbf);

  // ---- MoE: 2 batched GEMMs (direct f32 weights, 512-thread blocks) + combine ----
  gemm_up_kernel<<<dim3(kHID/64, kMaxTiles), 512, 0, stream>>>(
      tbf, w1, w3, hid, lists, counts, padbase, tileTab);
  gemm_down_kernel<<<dim3(kD/128, kMaxTiles), 512, 0, stream>>>(
      hid, w2, ffb, padbase, tileTab);
  moe_combine_kernel<<<kRows, 256, 0, stream>>>(
      ffb, padbase, packA, packB, cAv, cBv, outp);
}